// Round 1
// baseline (664.451 us; speedup 1.0000x reference)
//
#include <hip/hip_runtime.h>

#define DEV __device__ __forceinline__

typedef unsigned short u16;
typedef __attribute__((ext_vector_type(8))) __bf16 bf16x8;
typedef __attribute__((ext_vector_type(4))) float f32x4;

// ---------- helpers ----------
DEV u16 f2b(float f) {                       // f32 -> bf16 bits, RNE
    unsigned u = __builtin_bit_cast(unsigned, f);
    unsigned r = u + 0x7fffu + ((u >> 16) & 1u);
    return (u16)(r >> 16);
}

DEV f32x4 mfma16(bf16x8 a, bf16x8 b, f32x4 c) {
    return __builtin_amdgcn_mfma_f32_16x16x32_bf16(a, b, c, 0, 0, 0);
}

#define GLOAD_LDS16(gp, lp)                                                       \
    __builtin_amdgcn_global_load_lds((__attribute__((address_space(1))) void*)(gp), \
                                     (__attribute__((address_space(3))) void*)(lp), \
                                     16, 0, 0)

// ---------- f32 -> bf16 cast (vectorized) ----------
__global__ __launch_bounds__(256) void cast_k(const float4* __restrict__ in,
                                              ushort4* __restrict__ out, int n4) {
    int i = blockIdx.x * 256 + threadIdx.x;
    if (i < n4) {
        float4 v = in[i];
        ushort4 o;
        o.x = f2b(v.x); o.y = f2b(v.y); o.z = f2b(v.z); o.w = f2b(v.w);
        out[i] = o;
    }
}

// ---------- embedding + positional encoding ----------
// one thread per (row, d-pair); rows = B*T, 256 pairs per row (D=512)
__global__ __launch_bounds__(256) void embed_k(const int* __restrict__ tokens,
                                               const float* __restrict__ emb,
                                               float* __restrict__ xf,
                                               u16* __restrict__ xb) {
    int i   = blockIdx.x * 256 + threadIdx.x;   // pair index
    int row = i >> 8;                            // b*T + t
    int dp  = i & 255;                           // d pair: d0 = 2*dp
    int pos = row & 1023;                        // T = 1024
    int tok = tokens[row];
    const float* e = emb + (size_t)tok * 512 + dp * 2;
    float e0 = e[0] * 22.627416997969522f;       // sqrt(512)
    float e1 = e[1] * 22.627416997969522f;
    float freq = powf(10000.f, -(float)(2 * dp) * (1.f / 512.f));
    float ang  = (float)pos * freq;
    float v0 = e0 + sinf(ang);
    float v1 = e1 + cosf(ang);
    size_t o = (size_t)row * 512 + dp * 2;
    xf[o] = v0; xf[o + 1] = v1;
    xb[o] = f2b(v0); xb[o + 1] = f2b(v1);
}

// ---------- generic NT GEMM: C[M,N] = A[M,K](bf16) @ W[N,K](bf16)^T + bias ----------
// 128x128 tile, BK=32, 256 threads = 4 waves (2x2), each wave 64x64 out.
__global__ __launch_bounds__(256) void gemm_bt_k(const u16* __restrict__ A,
                                                 const u16* __restrict__ W,
                                                 const float* __restrict__ bias,
                                                 float* __restrict__ Cf,
                                                 u16* __restrict__ Cb,
                                                 int M, int N, int K, int relu) {
    __shared__ u16 sA[128 * 32];
    __shared__ u16 sB[128 * 32];
    const int m0 = blockIdx.x * 128;
    const int n0 = blockIdx.y * 128;
    const int tid  = threadIdx.x;
    const int lane = tid & 63;
    const int wid  = tid >> 6;
    const int wr = wid >> 1, wc = wid & 1;
    const int lg = lane >> 4, lr = lane & 15;

    f32x4 acc[4][4];
#pragma unroll
    for (int i = 0; i < 4; i++)
#pragma unroll
        for (int j = 0; j < 4; j++) acc[i][j] = (f32x4){0.f, 0.f, 0.f, 0.f};

    const int c0 = tid, c1 = tid + 256;          // 16B-chunk ids (512 chunks/tile)
    const int rA0 = c0 >> 2, kk0 = (c0 & 3) * 8; // row 0..127, k-offset 0/8/16/24
    const int rA1 = c1 >> 2, kk1 = (c1 & 3) * 8;

    for (int k0 = 0; k0 < K; k0 += 32) {
        GLOAD_LDS16(A + (size_t)(m0 + rA0) * K + k0 + kk0, sA + c0 * 8);
        GLOAD_LDS16(A + (size_t)(m0 + rA1) * K + k0 + kk1, sA + c1 * 8);
        GLOAD_LDS16(W + (size_t)(n0 + rA0) * K + k0 + kk0, sB + c0 * 8);
        GLOAD_LDS16(W + (size_t)(n0 + rA1) * K + k0 + kk1, sB + c1 * 8);
        __syncthreads();
        bf16x8 af[4], bfr[4];
#pragma unroll
        for (int mi = 0; mi < 4; mi++)
            af[mi] = *(const bf16x8*)(sA + (wr * 64 + mi * 16 + lr) * 32 + lg * 8);
#pragma unroll
        for (int ni = 0; ni < 4; ni++)
            bfr[ni] = *(const bf16x8*)(sB + (wc * 64 + ni * 16 + lr) * 32 + lg * 8);
#pragma unroll
        for (int mi = 0; mi < 4; mi++)
#pragma unroll
            for (int ni = 0; ni < 4; ni++)
                acc[mi][ni] = mfma16(af[mi], bfr[ni], acc[mi][ni]);
        __syncthreads();
    }

#pragma unroll
    for (int mi = 0; mi < 4; mi++) {
        const int rbase = m0 + wr * 64 + mi * 16 + lg * 4;
#pragma unroll
        for (int ni = 0; ni < 4; ni++) {
            const int col = n0 + wc * 64 + ni * 16 + lr;
            const float bv = bias[col];
#pragma unroll
            for (int r = 0; r < 4; r++) {
                float v = acc[mi][ni][r] + bv;
                if (relu) v = fmaxf(v, 0.f);
                if (Cf) Cf[(size_t)(rbase + r) * N + col] = v;
                if (Cb) Cb[(size_t)(rbase + r) * N + col] = f2b(v);
            }
        }
    }
}

// ---------- V transpose: [B*T, 512] bf16 -> VT [B,H,64,T] bf16 ----------
__global__ __launch_bounds__(256) void vt_k(const u16* __restrict__ V,
                                            u16* __restrict__ VT) {
    const int bh = blockIdx.x;           // b*8+h
    const int b = bh >> 3;
    const int h64 = (bh & 7) * 64;
    const int t0 = blockIdx.y * 64;
    __shared__ u16 s[64 * 65];
    const int tid = threadIdx.x;
#pragma unroll
    for (int i = 0; i < 16; i++) {
        int t = (tid >> 6) + i * 4;
        int d = tid & 63;
        s[d * 65 + t] = V[(size_t)(b * 1024 + t0 + t) * 512 + h64 + d];
    }
    __syncthreads();
#pragma unroll
    for (int i = 0; i < 16; i++) {
        int d = (tid >> 6) + i * 4;
        int t = tid & 63;
        VT[(size_t)(bh * 64 + d) * 1024 + t0 + t] = s[d * 65 + t];
    }
}

// ---------- flash attention, 1 wave per (b,h, 16 q-rows), 32 keys/iter ----------
// Q,K: bf16 [B*1024, 512] (head h at cols h*64..); VT: bf16 [B,H,64,LK]
// mask semantics match jnp.where(mask, finfo.min, s) -> softmax exactly.
template <int CAUSAL>
__global__ __launch_bounds__(64) void attn_k(const u16* __restrict__ Q,
                                             const u16* __restrict__ Kb,
                                             const u16* __restrict__ VT,
                                             const int* __restrict__ tokens,
                                             const signed char* __restrict__ km8,
                                             u16* __restrict__ O, int LK) {
    const int bh = blockIdx.x;
    const int b = bh >> 3;
    const int h64 = (bh & 7) * 64;
    const int qb = blockIdx.y;
    const int lane = threadIdx.x;
    const int lg = lane >> 4, lr = lane & 15;

    const u16* qrow = Q + (size_t)(b * 1024 + qb * 16 + lr) * 512 + h64 + lg * 8;
    const bf16x8 aq0 = *(const bf16x8*)(qrow);
    const bf16x8 aq1 = *(const bf16x8*)(qrow + 32);

    f32x4 o[4];
#pragma unroll
    for (int ni = 0; ni < 4; ni++) o[ni] = (f32x4){0.f, 0.f, 0.f, 0.f};
    float m_run[4], l_run[4];
#pragma unroll
    for (int r = 0; r < 4; r++) { m_run[r] = -3.402823466e38f; l_run[r] = 0.f; }

    __shared__ u16 sP[16 * 32];
    const u16* vbase = VT + (size_t)bh * 64 * LK;

    for (int k0 = 0; k0 < LK; k0 += 32) {
        f32x4 s[2];
#pragma unroll
        for (int c = 0; c < 2; c++) {
            const u16* krow =
                Kb + (size_t)(b * LK + k0 + c * 16 + lr) * 512 + h64 + lg * 8;
            bf16x8 bk0 = *(const bf16x8*)(krow);
            bf16x8 bk1 = *(const bf16x8*)(krow + 32);
            f32x4 t = (f32x4){0.f, 0.f, 0.f, 0.f};
            t = mfma16(aq0, bk0, t);
            t = mfma16(aq1, bk1, t);
            s[c] = t;
        }
        // scale + mask (lane holds rows q = qb*16+lg*4+r, col key = k0+c*16+lr)
#pragma unroll
        for (int c = 0; c < 2; c++) {
            const int key = k0 + c * 16 + lr;
            bool mkey;
            if (CAUSAL) mkey = (tokens[b * LK + key] == 0);
            else        mkey = (km8[b * LK + key] != 0);
#pragma unroll
            for (int r = 0; r < 4; r++) {
                float sv = s[c][r] * 0.125f;   // 1/sqrt(64)
                bool mk = mkey;
                if (CAUSAL) mk = mk || (key > qb * 16 + lg * 4 + r);
                s[c][r] = mk ? -3.402823466e38f : sv;
            }
        }
        // online softmax per q-row (each reg r is one row; 16-lane group reduce)
        float pf[4];
#pragma unroll
        for (int r = 0; r < 4; r++) {
            float bm = fmaxf(s[0][r], s[1][r]);
            bm = fmaxf(bm, __shfl_xor(bm, 1));
            bm = fmaxf(bm, __shfl_xor(bm, 2));
            bm = fmaxf(bm, __shfl_xor(bm, 4));
            bm = fmaxf(bm, __shfl_xor(bm, 8));
            float mn = fmaxf(m_run[r], bm);
            float sc = __expf(m_run[r] - mn);
            float p0 = __expf(s[0][r] - mn);
            float p1 = __expf(s[1][r] - mn);
            float bs = p0 + p1;
            bs += __shfl_xor(bs, 1);
            bs += __shfl_xor(bs, 2);
            bs += __shfl_xor(bs, 4);
            bs += __shfl_xor(bs, 8);
            l_run[r] = l_run[r] * sc + bs;
            m_run[r] = mn;
            pf[r] = sc;
            s[0][r] = p0; s[1][r] = p1;
        }
#pragma unroll
        for (int ni = 0; ni < 4; ni++)
#pragma unroll
            for (int r = 0; r < 4; r++) o[ni][r] *= pf[r];
        // redistribute P through LDS into PV A-fragment layout
        __syncthreads();
#pragma unroll
        for (int c = 0; c < 2; c++)
#pragma unroll
            for (int r = 0; r < 4; r++)
                sP[(lg * 4 + r) * 32 + c * 16 + lr] = f2b(s[c][r]);
        __syncthreads();
        bf16x8 ap = *(const bf16x8*)(sP + lr * 32 + lg * 8);
#pragma unroll
        for (int ni = 0; ni < 4; ni++) {
            bf16x8 bv =
                *(const bf16x8*)(vbase + (size_t)(ni * 16 + lr) * LK + k0 + lg * 8);
            o[ni] = mfma16(ap, bv, o[ni]);
        }
    }
#pragma unroll
    for (int ni = 0; ni < 4; ni++)
#pragma unroll
        for (int r = 0; r < 4; r++) {
            float v = o[ni][r] / l_run[r];
            O[(size_t)(b * 1024 + qb * 16 + lg * 4 + r) * 512 + h64 + ni * 16 + lr] =
                f2b(v);
        }
}

// ---------- fused residual + LayerNorm; writes f32 (opt) + bf16 ----------
__global__ __launch_bounds__(256) void ln_k(const float* __restrict__ a,
                                            const float* __restrict__ res,
                                            const float* __restrict__ g,
                                            const float* __restrict__ be,
                                            float* __restrict__ outf,
                                            u16* __restrict__ outb) {
    const int row = blockIdx.x;
    const int tid = threadIdx.x;
    const size_t base = (size_t)row * 512;
    float x0 = a[base + tid * 2] + res[base + tid * 2];
    float x1 = a[base + tid * 2 + 1] + res[base + tid * 2 + 1];
    float s = x0 + x1, q = x0 * x0 + x1 * x1;
#pragma unroll
    for (int off = 1; off < 64; off <<= 1) {
        s += __shfl_xor(s, off);
        q += __shfl_xor(q, off);
    }
    __shared__ float ps[8];
    const int wid = tid >> 6;
    if ((tid & 63) == 0) { ps[wid] = s; ps[wid + 4] = q; }
    __syncthreads();
    s = ps[0] + ps[1] + ps[2] + ps[3];
    q = ps[4] + ps[5] + ps[6] + ps[7];
    const float mu = s * (1.f / 512.f);
    const float var = q * (1.f / 512.f) - mu * mu;
    const float inv = rsqrtf(var + 1e-5f);
    float y0 = g[tid * 2] * (x0 - mu) * inv + be[tid * 2];
    float y1 = g[tid * 2 + 1] * (x1 - mu) * inv + be[tid * 2 + 1];
    if (outf) { outf[base + tid * 2] = y0; outf[base + tid * 2 + 1] = y1; }
    outb[base + tid * 2] = f2b(y0);
    outb[base + tid * 2 + 1] = f2b(y1);
}

// ---------- host ----------
extern "C" void kernel_launch(void* const* d_in, const int* in_sizes, int n_in,
                              void* d_out, int out_size, void* d_ws, size_t ws_size,
                              hipStream_t stream) {
    (void)in_sizes; (void)n_in; (void)out_size;
    const int*   tokens  = (const int*)d_in[0];
    const float* enc     = (const float*)d_in[1];
    const signed char* encmask = (const signed char*)d_in[2];
    const float* emb     = (const float*)d_in[3];
    const float* Wq  = (const float*)d_in[4];  const float* bq  = (const float*)d_in[5];
    const float* Wk  = (const float*)d_in[6];  const float* bk  = (const float*)d_in[7];
    const float* Wv  = (const float*)d_in[8];  const float* bv  = (const float*)d_in[9];
    const float* Wo1 = (const float*)d_in[10]; const float* bo1 = (const float*)d_in[11];
    const float* cWq = (const float*)d_in[12]; const float* cbq = (const float*)d_in[13];
    const float* eWk = (const float*)d_in[14]; const float* ebk = (const float*)d_in[15];
    const float* eWv = (const float*)d_in[16]; const float* ebv = (const float*)d_in[17];
    const float* Wo2 = (const float*)d_in[18]; const float* bo2 = (const float*)d_in[19];
    const float* W1  = (const float*)d_in[20]; const float* b1  = (const float*)d_in[21];
    const float* W2  = (const float*)d_in[22]; const float* b2  = (const float*)d_in[23];
    const float* g1  = (const float*)d_in[24]; const float* be1 = (const float*)d_in[25];
    const float* g2  = (const float*)d_in[26]; const float* be2 = (const float*)d_in[27];
    const float* g3  = (const float*)d_in[28]; const float* be3 = (const float*)d_in[29];
    const float* Wout= (const float*)d_in[30]; const float* bout= (const float*)d_in[31];
    float* out = (float*)d_out;

    char* ws = (char*)d_ws;
    size_t off = 0;
    auto alloc = [&](size_t bytes) -> void* {
        void* p = ws + off;
        off += (bytes + 255) & ~(size_t)255;
        return p;
    };

    u16* Wqb  = (u16*)alloc(262144 * 2);
    u16* Wkb  = (u16*)alloc(262144 * 2);
    u16* Wvb  = (u16*)alloc(262144 * 2);
    u16* Wo1b = (u16*)alloc(262144 * 2);
    u16* cWqb = (u16*)alloc(262144 * 2);
    u16* eWkb = (u16*)alloc(262144 * 2);
    u16* eWvb = (u16*)alloc(262144 * 2);
    u16* Wo2b = (u16*)alloc(262144 * 2);
    u16* W1b  = (u16*)alloc(524288 * 2);
    u16* W2b  = (u16*)alloc(524288 * 2);
    u16* Woutb= (u16*)alloc((size_t)16384000 * 2);
    u16* encb = (u16*)alloc((size_t)2097152 * 2);
    float* x0f = (float*)alloc((size_t)2097152 * 4);
    u16*   x0b = (u16*)alloc((size_t)2097152 * 2);
    float* x1f = (float*)alloc((size_t)2097152 * 4);
    u16*   x1b = (u16*)alloc((size_t)2097152 * 2);
    float* x2f = (float*)alloc((size_t)2097152 * 4);
    u16*   x2b = (u16*)alloc((size_t)2097152 * 2);
    u16*   x3b = (u16*)alloc((size_t)2097152 * 2);
    u16* t0 = (u16*)alloc((size_t)2097152 * 2);   // qb  / ekb
    u16* t1 = (u16*)alloc((size_t)2097152 * 2);   // kb  / evb
    u16* t2 = (u16*)alloc((size_t)2097152 * 2);   // vb  / vt2
    u16* t3 = (u16*)alloc((size_t)2097152 * 2);   // vt1 / cqb
    u16* t4 = (u16*)alloc((size_t)2097152 * 2);   // sab / cab
    float* p8 = (float*)alloc((size_t)2097152 * 4); // p1f / p2f / ffn-out
    u16*  hb  = (u16*)alloc((size_t)4194304 * 2);   // relu hidden [4096,1024]
    if (off > ws_size) return; // ws too small: bail (bench will flag)

    auto cast = [&](const float* src, u16* dst, size_t n) {
        int n4 = (int)(n / 4);
        cast_k<<<(n4 + 255) / 256, 256, 0, stream>>>((const float4*)src,
                                                     (ushort4*)dst, n4);
    };
    cast(Wq, Wqb, 262144);   cast(Wk, Wkb, 262144);   cast(Wv, Wvb, 262144);
    cast(Wo1, Wo1b, 262144); cast(cWq, cWqb, 262144); cast(eWk, eWkb, 262144);
    cast(eWv, eWvb, 262144); cast(Wo2, Wo2b, 262144); cast(W1, W1b, 524288);
    cast(W2, W2b, 524288);   cast(Wout, Woutb, 16384000); cast(enc, encb, 2097152);

    embed_k<<<4096, 256, 0, stream>>>(tokens, emb, x0f, x0b);

    auto gemm = [&](const u16* A, const u16* Wb, const float* bias, float* Cf,
                    u16* Cb, int M, int N, int K, int relu) {
        gemm_bt_k<<<dim3(M / 128, N / 128), 256, 0, stream>>>(A, Wb, bias, Cf, Cb,
                                                              M, N, K, relu);
    };

    // self-attention block
    gemm(x0b, Wqb, bq, nullptr, t0, 4096, 512, 512, 0);
    gemm(x0b, Wkb, bk, nullptr, t1, 4096, 512, 512, 0);
    gemm(x0b, Wvb, bv, nullptr, t2, 4096, 512, 512, 0);
    vt_k<<<dim3(32, 16), 256, 0, stream>>>(t2, t3);
    attn_k<1><<<dim3(32, 64), 64, 0, stream>>>(t0, t1, t3, tokens, nullptr, t4, 1024);
    gemm(t4, Wo1b, bo1, p8, nullptr, 4096, 512, 512, 0);
    ln_k<<<4096, 256, 0, stream>>>(p8, x0f, g1, be1, x1f, x1b);

    // cross-attention block
    gemm(encb, eWkb, ebk, nullptr, t0, 4096, 512, 512, 0);
    gemm(encb, eWvb, ebv, nullptr, t1, 4096, 512, 512, 0);
    vt_k<<<dim3(32, 16), 256, 0, stream>>>(t1, t2);
    gemm(x1b, cWqb, cbq, nullptr, t3, 4096, 512, 512, 0);
    attn_k<0><<<dim3(32, 64), 64, 0, stream>>>(t3, t0, t2, nullptr, encmask, t4, 1024);
    gemm(t4, Wo2b, bo2, p8, nullptr, 4096, 512, 512, 0);
    ln_k<<<4096, 256, 0, stream>>>(p8, x1f, g3, be3, x2f, x2b);

    // FFN
    gemm(x2b, W1b, b1, nullptr, hb, 4096, 1024, 512, 1);
    gemm(hb, W2b, b2, p8, nullptr, 4096, 512, 1024, 0);
    ln_k<<<4096, 256, 0, stream>>>(p8, x2f, g2, be2, nullptr, x3b);

    // vocab projection
    gemm(x3b, Woutb, bout, out, nullptr, 4096, 32000, 512, 0);
}

// Round 2
// 617.467 us; speedup vs baseline: 1.0761x; 1.0761x over previous
//
#include <hip/hip_runtime.h>

#define DEV __device__ __forceinline__

typedef unsigned short u16;
typedef __attribute__((ext_vector_type(8))) __bf16 bf16x8;
typedef __attribute__((ext_vector_type(4))) float f32x4;

// ---------- helpers ----------
DEV u16 f2b(float f) {                       // f32 -> bf16 bits, RNE
    unsigned u = __builtin_bit_cast(unsigned, f);
    unsigned r = u + 0x7fffu + ((u >> 16) & 1u);
    return (u16)(r >> 16);
}

DEV f32x4 mfma16(bf16x8 a, bf16x8 b, f32x4 c) {
    return __builtin_amdgcn_mfma_f32_16x16x32_bf16(a, b, c, 0, 0, 0);
}

#define GLOAD_LDS16(gp, lp)                                                       \
    __builtin_amdgcn_global_load_lds((__attribute__((address_space(1))) void*)(gp), \
                                     (__attribute__((address_space(3))) void*)(lp), \
                                     16, 0, 0)

// ---------- merged f32 -> bf16 cast over 12 regions ----------
struct CastArgs {
    const float4* src[12];
    ushort4* dst[12];
    int start4[13];   // cumulative float4 offsets; start4[12] = total
};

__global__ __launch_bounds__(256) void cast_all_k(CastArgs a) {
    const int total = a.start4[12];
    for (int i = blockIdx.x * 256 + threadIdx.x; i < total; i += gridDim.x * 256) {
        int j = 0;
#pragma unroll
        for (int t = 1; t < 12; t++) j += (i >= a.start4[t]) ? 1 : 0;
        const int loc = i - a.start4[j];
        float4 v = a.src[j][loc];
        ushort4 o;
        o.x = f2b(v.x); o.y = f2b(v.y); o.z = f2b(v.z); o.w = f2b(v.w);
        a.dst[j][loc] = o;
    }
}

// ---------- embedding + positional encoding ----------
__global__ __launch_bounds__(256) void embed_k(const int* __restrict__ tokens,
                                               const float* __restrict__ emb,
                                               float* __restrict__ xf,
                                               u16* __restrict__ xb) {
    int i   = blockIdx.x * 256 + threadIdx.x;   // pair index
    int row = i >> 8;                            // b*T + t
    int dp  = i & 255;                           // d pair: d0 = 2*dp
    int pos = row & 1023;                        // T = 1024
    int tok = tokens[row];
    const float* e = emb + (size_t)tok * 512 + dp * 2;
    float e0 = e[0] * 22.627416997969522f;       // sqrt(512)
    float e1 = e[1] * 22.627416997969522f;
    // freq = 10000^(-2dp/512) = exp2(-dp * log2(10000)/256)
    float freq = exp2f(-(float)dp * 0.05190512648262190f);
    float ang  = (float)pos * freq;
    float v0 = e0 + __sinf(ang);
    float v1 = e1 + __cosf(ang);
    size_t o = (size_t)row * 512 + dp * 2;
    xf[o] = v0; xf[o + 1] = v1;
    xb[o] = f2b(v0); xb[o + 1] = f2b(v1);
}

// ---------- generic NT GEMM: C[M,N] = A[M,K](bf16) @ W[N,K](bf16)^T + bias ----------
// 128x128 tile, BK=32, 4 waves. XCD-aware bijective block swizzle (T1/m204).
// bias selected per 512-col group (b1/b2 optional) for fused QKV / eKV GEMMs.
__global__ __launch_bounds__(256) void gemm_bt_k(const u16* __restrict__ A,
                                                 const u16* __restrict__ W,
                                                 const float* __restrict__ b0,
                                                 const float* __restrict__ b1,
                                                 const float* __restrict__ b2,
                                                 float* __restrict__ Cf,
                                                 u16* __restrict__ Cb,
                                                 int M, int N, int K, int relu) {
    __shared__ u16 sA[128 * 32];
    __shared__ u16 sB[128 * 32];
    // XCD swizzle: consecutive chunk ids on one XCD share tn (same W panel)
    const int gx = gridDim.x;
    const int nwg = gx * gridDim.y;
    const int orig = blockIdx.y * gx + blockIdx.x;
    const int xcd = orig & 7, chunk = orig >> 3;
    const int q = nwg >> 3, r = nwg & 7;
    const int wgid = (xcd < r ? xcd * (q + 1) : r * (q + 1) + (xcd - r) * q) + chunk;
    const int m0 = (wgid % gx) * 128;
    const int n0 = (wgid / gx) * 128;

    const int tid  = threadIdx.x;
    const int lane = tid & 63;
    const int wid  = tid >> 6;
    const int wr = wid >> 1, wc = wid & 1;
    const int lg = lane >> 4, lr = lane & 15;

    f32x4 acc[4][4];
#pragma unroll
    for (int i = 0; i < 4; i++)
#pragma unroll
        for (int j = 0; j < 4; j++) acc[i][j] = (f32x4){0.f, 0.f, 0.f, 0.f};

    const int c0 = tid, c1 = tid + 256;          // 16B-chunk ids (512 chunks/tile)
    const int rA0 = c0 >> 2, kk0 = (c0 & 3) * 8;
    const int rA1 = c1 >> 2, kk1 = (c1 & 3) * 8;

    for (int k0 = 0; k0 < K; k0 += 32) {
        GLOAD_LDS16(A + (size_t)(m0 + rA0) * K + k0 + kk0, sA + c0 * 8);
        GLOAD_LDS16(A + (size_t)(m0 + rA1) * K + k0 + kk1, sA + c1 * 8);
        GLOAD_LDS16(W + (size_t)(n0 + rA0) * K + k0 + kk0, sB + c0 * 8);
        GLOAD_LDS16(W + (size_t)(n0 + rA1) * K + k0 + kk1, sB + c1 * 8);
        __syncthreads();
        bf16x8 af[4], bfr[4];
#pragma unroll
        for (int mi = 0; mi < 4; mi++)
            af[mi] = *(const bf16x8*)(sA + (wr * 64 + mi * 16 + lr) * 32 + lg * 8);
#pragma unroll
        for (int ni = 0; ni < 4; ni++)
            bfr[ni] = *(const bf16x8*)(sB + (wc * 64 + ni * 16 + lr) * 32 + lg * 8);
#pragma unroll
        for (int mi = 0; mi < 4; mi++)
#pragma unroll
            for (int ni = 0; ni < 4; ni++)
                acc[mi][ni] = mfma16(af[mi], bfr[ni], acc[mi][ni]);
        __syncthreads();
    }

#pragma unroll
    for (int mi = 0; mi < 4; mi++) {
        const int rbase = m0 + wr * 64 + mi * 16 + lg * 4;
#pragma unroll
        for (int ni = 0; ni < 4; ni++) {
            const int col = n0 + wc * 64 + ni * 16 + lr;
            const float* bp = b0; int cc = col;
            if (b1 && col >= 512)  { bp = b1; cc = col - 512; }
            if (b2 && col >= 1024) { bp = b2; cc = col - 1024; }
            const float bv = bp[cc];
#pragma unroll
            for (int rr = 0; rr < 4; rr++) {
                float v = acc[mi][ni][rr] + bv;
                if (relu) v = fmaxf(v, 0.f);
                if (Cf) Cf[(size_t)(rbase + rr) * N + col] = v;
                if (Cb) Cb[(size_t)(rbase + rr) * N + col] = f2b(v);
            }
        }
    }
}

// ---------- V transpose: [B*T, rs] bf16 (64-col slice) -> VT [B,H,64,1024] ----------
__global__ __launch_bounds__(256) void vt_k(const u16* __restrict__ V, int rs,
                                            u16* __restrict__ VT) {
    const int bh = blockIdx.x;           // b*8+h
    const int b = bh >> 3;
    const int h64 = (bh & 7) * 64;
    const int t0 = blockIdx.y * 64;
    __shared__ u16 s[64 * 65];
    const int tid = threadIdx.x;
#pragma unroll
    for (int i = 0; i < 16; i++) {
        int t = (tid >> 6) + i * 4;
        int d = tid & 63;
        s[d * 65 + t] = V[(size_t)(b * 1024 + t0 + t) * rs + h64 + d];
    }
    __syncthreads();
#pragma unroll
    for (int i = 0; i < 16; i++) {
        int d = (tid >> 6) + i * 4;
        int t = tid & 63;
        VT[(size_t)(bh * 64 + d) * 1024 + t0 + t] = s[d * 65 + t];
    }
}

// ---------- flash attention, 1 wave per (b,h, 16 q-rows), 32 keys/iter ----------
// Causal version skips fully-future key blocks; exact fallback for the
// fully-masked-row edge case (all-PAD prefix) via __any + continued loop.
template <int CAUSAL>
__global__ __launch_bounds__(64) void attn_k(const u16* __restrict__ Q, int qrs,
                                             const u16* __restrict__ Kb, int krs,
                                             const u16* __restrict__ VT,
                                             const int* __restrict__ tokens,
                                             const signed char* __restrict__ km8,
                                             u16* __restrict__ O, int LK) {
    const int bh = blockIdx.x;
    const int b = bh >> 3;
    const int h64 = (bh & 7) * 64;
    const int qb = blockIdx.y;
    const int lane = threadIdx.x;
    const int lg = lane >> 4, lr = lane & 15;
    const float NEG = -3.402823466e38f;

    const u16* qrow = Q + (size_t)(b * 1024 + qb * 16 + lr) * qrs + h64 + lg * 8;
    const bf16x8 aq0 = *(const bf16x8*)(qrow);
    const bf16x8 aq1 = *(const bf16x8*)(qrow + 32);

    f32x4 o[4];
#pragma unroll
    for (int ni = 0; ni < 4; ni++) o[ni] = (f32x4){0.f, 0.f, 0.f, 0.f};
    float m_run[4], l_run[4];
#pragma unroll
    for (int rr = 0; rr < 4; rr++) { m_run[rr] = NEG; l_run[rr] = 0.f; }

    __shared__ u16 sP[16 * 32];
    const u16* vbase = VT + (size_t)bh * 64 * LK;

    auto body = [&](int k0) {
        f32x4 s[2];
#pragma unroll
        for (int c = 0; c < 2; c++) {
            const u16* krow =
                Kb + (size_t)(b * LK + k0 + c * 16 + lr) * krs + h64 + lg * 8;
            bf16x8 bk0 = *(const bf16x8*)(krow);
            bf16x8 bk1 = *(const bf16x8*)(krow + 32);
            f32x4 t = (f32x4){0.f, 0.f, 0.f, 0.f};
            t = mfma16(aq0, bk0, t);
            t = mfma16(aq1, bk1, t);
            s[c] = t;
        }
#pragma unroll
        for (int c = 0; c < 2; c++) {
            const int key = k0 + c * 16 + lr;
            bool mkey;
            if (CAUSAL) mkey = (tokens[b * LK + key] == 0);
            else        mkey = (km8[b * LK + key] != 0);
#pragma unroll
            for (int rr = 0; rr < 4; rr++) {
                float sv = s[c][rr] * 0.125f;   // 1/sqrt(64)
                bool mk = mkey;
                if (CAUSAL) mk = mk || (key > qb * 16 + lg * 4 + rr);
                s[c][rr] = mk ? NEG : sv;
            }
        }
        float pf[4];
#pragma unroll
        for (int rr = 0; rr < 4; rr++) {
            float bm = fmaxf(s[0][rr], s[1][rr]);
            bm = fmaxf(bm, __shfl_xor(bm, 1));
            bm = fmaxf(bm, __shfl_xor(bm, 2));
            bm = fmaxf(bm, __shfl_xor(bm, 4));
            bm = fmaxf(bm, __shfl_xor(bm, 8));
            float mn = fmaxf(m_run[rr], bm);
            float sc = __expf(m_run[rr] - mn);
            float p0 = __expf(s[0][rr] - mn);
            float p1 = __expf(s[1][rr] - mn);
            float bs = p0 + p1;
            bs += __shfl_xor(bs, 1);
            bs += __shfl_xor(bs, 2);
            bs += __shfl_xor(bs, 4);
            bs += __shfl_xor(bs, 8);
            l_run[rr] = l_run[rr] * sc + bs;
            m_run[rr] = mn;
            pf[rr] = sc;
            s[0][rr] = p0; s[1][rr] = p1;
        }
#pragma unroll
        for (int ni = 0; ni < 4; ni++)
#pragma unroll
            for (int rr = 0; rr < 4; rr++) o[ni][rr] *= pf[rr];
        __syncthreads();
#pragma unroll
        for (int c = 0; c < 2; c++)
#pragma unroll
            for (int rr = 0; rr < 4; rr++)
                sP[(lg * 4 + rr) * 32 + c * 16 + lr] = f2b(s[c][rr]);
        __syncthreads();
        bf16x8 ap = *(const bf16x8*)(sP + lr * 32 + lg * 8);
#pragma unroll
        for (int ni = 0; ni < 4; ni++) {
            bf16x8 bv =
                *(const bf16x8*)(vbase + (size_t)(ni * 16 + lr) * LK + k0 + lg * 8);
            o[ni] = mfma16(ap, bv, o[ni]);
        }
    };

    int kend = CAUSAL ? (((qb * 16 + 15) >> 5) + 1) * 32 : LK;
    if (kend > LK) kend = LK;
    for (int k0 = 0; k0 < kend; k0 += 32) body(k0);
    if (CAUSAL && kend < LK) {
        // exact fully-masked-row fallback (all-PAD prefix): continue the loop.
        bool fm = (m_run[0] == NEG) || (m_run[1] == NEG) ||
                  (m_run[2] == NEG) || (m_run[3] == NEG);
        if (__any(fm))
            for (int k0 = kend; k0 < LK; k0 += 32) body(k0);
    }

#pragma unroll
    for (int ni = 0; ni < 4; ni++)
#pragma unroll
        for (int rr = 0; rr < 4; rr++) {
            float v = o[ni][rr] / l_run[rr];
            O[(size_t)(b * 1024 + qb * 16 + lg * 4 + rr) * 512 + h64 + ni * 16 + lr] =
                f2b(v);
        }
}

// ---------- fused residual + LayerNorm; writes f32 (opt) + bf16 ----------
__global__ __launch_bounds__(256) void ln_k(const float* __restrict__ a,
                                            const float* __restrict__ res,
                                            const float* __restrict__ g,
                                            const float* __restrict__ be,
                                            float* __restrict__ outf,
                                            u16* __restrict__ outb) {
    const int row = blockIdx.x;
    const int tid = threadIdx.x;
    const size_t base = (size_t)row * 512;
    float2 av = ((const float2*)(a + base))[tid];
    float2 rv = ((const float2*)(res + base))[tid];
    float x0 = av.x + rv.x;
    float x1 = av.y + rv.y;
    float s = x0 + x1, q = x0 * x0 + x1 * x1;
#pragma unroll
    for (int off = 1; off < 64; off <<= 1) {
        s += __shfl_xor(s, off);
        q += __shfl_xor(q, off);
    }
    __shared__ float ps[8];
    const int wid = tid >> 6;
    if ((tid & 63) == 0) { ps[wid] = s; ps[wid + 4] = q; }
    __syncthreads();
    s = ps[0] + ps[1] + ps[2] + ps[3];
    q = ps[4] + ps[5] + ps[6] + ps[7];
    const float mu = s * (1.f / 512.f);
    const float var = q * (1.f / 512.f) - mu * mu;
    const float inv = rsqrtf(var + 1e-5f);
    float2 gv = ((const float2*)g)[tid];
    float2 bv = ((const float2*)be)[tid];
    float y0 = gv.x * (x0 - mu) * inv + bv.x;
    float y1 = gv.y * (x1 - mu) * inv + bv.y;
    if (outf) { ((float2*)(outf + base))[tid] = make_float2(y0, y1); }
    outb[base + tid * 2] = f2b(y0);
    outb[base + tid * 2 + 1] = f2b(y1);
}

// ---------- host ----------
extern "C" void kernel_launch(void* const* d_in, const int* in_sizes, int n_in,
                              void* d_out, int out_size, void* d_ws, size_t ws_size,
                              hipStream_t stream) {
    (void)in_sizes; (void)n_in; (void)out_size;
    const int*   tokens  = (const int*)d_in[0];
    const float* enc     = (const float*)d_in[1];
    const signed char* encmask = (const signed char*)d_in[2];
    const float* emb     = (const float*)d_in[3];
    const float* Wq  = (const float*)d_in[4];  const float* bq  = (const float*)d_in[5];
    const float* Wk  = (const float*)d_in[6];  const float* bk  = (const float*)d_in[7];
    const float* Wv  = (const float*)d_in[8];  const float* bv  = (const float*)d_in[9];
    const float* Wo1 = (const float*)d_in[10]; const float* bo1 = (const float*)d_in[11];
    const float* cWq = (const float*)d_in[12]; const float* cbq = (const float*)d_in[13];
    const float* eWk = (const float*)d_in[14]; const float* ebk = (const float*)d_in[15];
    const float* eWv = (const float*)d_in[16]; const float* ebv = (const float*)d_in[17];
    const float* Wo2 = (const float*)d_in[18]; const float* bo2 = (const float*)d_in[19];
    const float* W1  = (const float*)d_in[20]; const float* b1  = (const float*)d_in[21];
    const float* W2  = (const float*)d_in[22]; const float* b2  = (const float*)d_in[23];
    const float* g1  = (const float*)d_in[24]; const float* be1 = (const float*)d_in[25];
    const float* g2  = (const float*)d_in[26]; const float* be2 = (const float*)d_in[27];
    const float* g3  = (const float*)d_in[28]; const float* be3 = (const float*)d_in[29];
    const float* Wout= (const float*)d_in[30]; const float* bout= (const float*)d_in[31];
    float* out = (float*)d_out;

    char* ws = (char*)d_ws;
    size_t off = 0;
    auto alloc = [&](size_t bytes) -> void* {
        void* p = ws + off;
        off += (bytes + 255) & ~(size_t)255;
        return p;
    };

    u16* Wqkvb = (u16*)alloc((size_t)786432 * 2);        // [1536,512]
    u16* Wo1b  = (u16*)alloc(262144 * 2);
    u16* cWqb  = (u16*)alloc(262144 * 2);
    u16* eWkvb = (u16*)alloc((size_t)524288 * 2);        // [1024,512]
    u16* Wo2b  = (u16*)alloc(262144 * 2);
    u16* W1b   = (u16*)alloc(524288 * 2);
    u16* W2b   = (u16*)alloc(524288 * 2);
    u16* Woutb = (u16*)alloc((size_t)16384000 * 2);
    u16* encb  = (u16*)alloc((size_t)2097152 * 2);
    float* x0f = (float*)alloc((size_t)2097152 * 4);
    u16*   x0b = (u16*)alloc((size_t)2097152 * 2);
    float* x1f = (float*)alloc((size_t)2097152 * 4);
    u16*   x1b = (u16*)alloc((size_t)2097152 * 2);
    float* x2f = (float*)alloc((size_t)2097152 * 4);
    u16*   x2b = (u16*)alloc((size_t)2097152 * 2);
    u16*   x3b = (u16*)alloc((size_t)2097152 * 2);
    u16* qkv = (u16*)alloc((size_t)4096 * 1536 * 2);     // fused q|k|v
    u16* ekv = (u16*)alloc((size_t)4096 * 1024 * 2);     // fused ek|ev
    u16* cq  = (u16*)alloc((size_t)2097152 * 2);
    u16* vt  = (u16*)alloc((size_t)2097152 * 2);         // reused for both attns
    u16* t4  = (u16*)alloc((size_t)2097152 * 2);         // attn out (reused)
    float* p8 = (float*)alloc((size_t)2097152 * 4);
    u16*  hb  = (u16*)alloc((size_t)4194304 * 2);        // relu hidden [4096,1024]
    if (off > ws_size) return;

    // merged weight/enc casts (12 regions, one launch)
    CastArgs ca;
    const float* srcs[12] = {Wq, Wk, Wv, Wo1, cWq, eWk, eWv, Wo2, W1, W2, enc, Wout};
    u16* dsts[12] = {Wqkvb, Wqkvb + 262144, Wqkvb + 524288, Wo1b, cWqb,
                     eWkvb, eWkvb + 262144, Wo2b, W1b, W2b, encb, Woutb};
    int ns[12] = {262144, 262144, 262144, 262144, 262144, 262144, 262144, 262144,
                  524288, 524288, 2097152, 16384000};
    int acc4 = 0;
    for (int j = 0; j < 12; j++) {
        ca.src[j] = (const float4*)srcs[j];
        ca.dst[j] = (ushort4*)dsts[j];
        ca.start4[j] = acc4;
        acc4 += ns[j] / 4;
    }
    ca.start4[12] = acc4;
    cast_all_k<<<2048, 256, 0, stream>>>(ca);

    embed_k<<<4096, 256, 0, stream>>>(tokens, emb, x0f, x0b);

    auto gemm = [&](const u16* A, const u16* Wb, const float* bb0, const float* bb1,
                    const float* bb2, float* Cf, u16* Cb, int M, int N, int K,
                    int relu) {
        gemm_bt_k<<<dim3(M / 128, N / 128), 256, 0, stream>>>(A, Wb, bb0, bb1, bb2,
                                                              Cf, Cb, M, N, K, relu);
    };

    // self-attention block (fused QKV)
    gemm(x0b, Wqkvb, bq, bk, bv, nullptr, qkv, 4096, 1536, 512, 0);
    vt_k<<<dim3(32, 16), 256, 0, stream>>>(qkv + 1024, 1536, vt);
    attn_k<1><<<dim3(32, 64), 64, 0, stream>>>(qkv, 1536, qkv + 512, 1536, vt,
                                               tokens, nullptr, t4, 1024);
    gemm(t4, Wo1b, bo1, nullptr, nullptr, p8, nullptr, 4096, 512, 512, 0);
    ln_k<<<4096, 256, 0, stream>>>(p8, x0f, g1, be1, x1f, x1b);

    // cross-attention block (fused eK/eV)
    gemm(encb, eWkvb, ebk, ebv, nullptr, nullptr, ekv, 4096, 1024, 512, 0);
    vt_k<<<dim3(32, 16), 256, 0, stream>>>(ekv + 512, 1024, vt);
    gemm(x1b, cWqb, cbq, nullptr, nullptr, nullptr, cq, 4096, 512, 512, 0);
    attn_k<0><<<dim3(32, 64), 64, 0, stream>>>(cq, 512, ekv, 1024, vt,
                                               nullptr, encmask, t4, 1024);
    gemm(t4, Wo2b, bo2, nullptr, nullptr, p8, nullptr, 4096, 512, 512, 0);
    ln_k<<<4096, 256, 0, stream>>>(p8, x1f, g3, be3, x2f, x2b);

    // FFN
    gemm(x2b, W1b, b1, nullptr, nullptr, nullptr, hb, 4096, 1024, 512, 1);
    gemm(hb, W2b, b2, nullptr, nullptr, p8, nullptr, 4096, 512, 1024, 0);
    ln_k<<<4096, 256, 0, stream>>>(p8, x2f, g2, be2, nullptr, x3b);

    // vocab projection
    gemm(x3b, Woutb, bout, nullptr, nullptr, out, nullptr, 4096, 32000, 512, 0);
}

// Round 3
// 586.716 us; speedup vs baseline: 1.1325x; 1.0524x over previous
//
#include <hip/hip_runtime.h>

#define DEV __device__ __forceinline__

typedef unsigned short u16;
typedef __attribute__((ext_vector_type(8))) __bf16 bf16x8;
typedef __attribute__((ext_vector_type(4))) float f32x4;

// ---------- helpers ----------
DEV u16 f2b(float f) {                       // f32 -> bf16 bits, RNE
    unsigned u = __builtin_bit_cast(unsigned, f);
    unsigned r = u + 0x7fffu + ((u >> 16) & 1u);
    return (u16)(r >> 16);
}

DEV f32x4 mfma16(bf16x8 a, bf16x8 b, f32x4 c) {
    return __builtin_amdgcn_mfma_f32_16x16x32_bf16(a, b, c, 0, 0, 0);
}

#define GLOAD_LDS16(gp, lp)                                                       \
    __builtin_amdgcn_global_load_lds((__attribute__((address_space(1))) void*)(gp), \
                                     (__attribute__((address_space(3))) void*)(lp), \
                                     16, 0, 0)

// ---------- merged f32 -> bf16 cast over 12 regions ----------
struct CastArgs {
    const float4* src[12];
    ushort4* dst[12];
    int start4[13];   // cumulative float4 offsets; start4[12] = total
};

__global__ __launch_bounds__(256) void cast_all_k(CastArgs a) {
    const int total = a.start4[12];
    for (int i = blockIdx.x * 256 + threadIdx.x; i < total; i += gridDim.x * 256) {
        int j = 0;
#pragma unroll
        for (int t = 1; t < 12; t++) j += (i >= a.start4[t]) ? 1 : 0;
        const int loc = i - a.start4[j];
        float4 v = a.src[j][loc];
        ushort4 o;
        o.x = f2b(v.x); o.y = f2b(v.y); o.z = f2b(v.z); o.w = f2b(v.w);
        a.dst[j][loc] = o;
    }
}

// ---------- embedding + positional encoding ----------
__global__ __launch_bounds__(256) void embed_k(const int* __restrict__ tokens,
                                               const float* __restrict__ emb,
                                               float* __restrict__ xf,
                                               u16* __restrict__ xb) {
    int i   = blockIdx.x * 256 + threadIdx.x;   // pair index
    int row = i >> 8;                            // b*T + t
    int dp  = i & 255;                           // d pair: d0 = 2*dp
    int pos = row & 1023;                        // T = 1024
    int tok = tokens[row];
    const float* e = emb + (size_t)tok * 512 + dp * 2;
    float e0 = e[0] * 22.627416997969522f;       // sqrt(512)
    float e1 = e[1] * 22.627416997969522f;
    float freq = exp2f(-(float)dp * 0.05190512648262190f);  // 10000^(-2dp/512)
    float ang  = (float)pos * freq;
    float v0 = e0 + __sinf(ang);
    float v1 = e1 + __cosf(ang);
    size_t o = (size_t)row * 512 + dp * 2;
    xf[o] = v0; xf[o + 1] = v1;
    xb[o] = f2b(v0); xb[o + 1] = f2b(v1);
}

// ---------- generic NT GEMM: C[M,N] = A[M,K](bf16) @ W[N,K](bf16)^T + bias ----------
// BM x BN tile, BK=32, 4 waves (2x2, each wave BM/2 x BN/2).
// Double-buffered LDS, 1 barrier/iter (T3-min). XOR bank swizzle via
// pre-swizzled GLOBAL source + matching swizzled ds_read (rule #21).
// XCD-aware bijective block swizzle (T1/m204).
template <int BM, int BN>
__global__ __launch_bounds__(256) void gemm_bt_k(const u16* __restrict__ A,
                                                 const u16* __restrict__ W,
                                                 const float* __restrict__ b0,
                                                 const float* __restrict__ b1,
                                                 const float* __restrict__ b2,
                                                 float* __restrict__ Cf,
                                                 u16* __restrict__ Cb,
                                                 int M, int N, int K, int relu) {
    constexpr int MF = BM / 32;      // m-frags per wave
    constexpr int NF = BN / 32;      // n-frags per wave
    constexpr int CH_A = BM * 4;     // 16B chunks per A tile (BK=32)
    constexpr int CH_TOT = (BM + BN) * 4;
    __shared__ u16 sA[2][BM * 32];
    __shared__ u16 sB[2][BN * 32];

    const int gx = gridDim.x;
    const int nwg = gx * gridDim.y;
    const int orig = blockIdx.y * gx + blockIdx.x;
    const int xcd = orig & 7, chnk = orig >> 3;
    const int q = nwg >> 3, r = nwg & 7;
    const int wgid = (xcd < r ? xcd * (q + 1) : r * (q + 1) + (xcd - r) * q) + chnk;
    const int m0 = (wgid % gx) * BM;
    const int n0 = (wgid / gx) * BN;

    const int tid  = threadIdx.x;
    const int lane = tid & 63;
    const int wid  = tid >> 6;
    const int wr = wid >> 1, wc = wid & 1;
    const int lg = lane >> 4, lr = lane & 15;

    f32x4 acc[MF][NF];
#pragma unroll
    for (int i = 0; i < MF; i++)
#pragma unroll
        for (int j = 0; j < NF; j++) acc[i][j] = (f32x4){0.f, 0.f, 0.f, 0.f};

    auto stage = [&](int buf, int k0) {
#pragma unroll
        for (int c = tid; c < CH_TOT; c += 256) {
            if (c < CH_A) {
                const int row = c >> 2, ch = c & 3;
                const int gch = ch ^ ((row >> 1) & 3);
                GLOAD_LDS16(A + (size_t)(m0 + row) * K + k0 + gch * 8,
                            &sA[buf][c * 8]);
            } else {
                const int cb = c - CH_A;
                const int row = cb >> 2, ch = cb & 3;
                const int gch = ch ^ ((row >> 1) & 3);
                GLOAD_LDS16(W + (size_t)(n0 + row) * K + k0 + gch * 8,
                            &sB[buf][cb * 8]);
            }
        }
    };

    const int nt = K >> 5;
    stage(0, 0);
    int cur = 0;
    for (int t = 0; t < nt; t++) {
        __syncthreads();                      // drains prev stage (vmcnt+lgkm)
        if (t + 1 < nt) stage(cur ^ 1, (t + 1) << 5);   // overlap with compute
        bf16x8 af[MF], bfr[NF];
#pragma unroll
        for (int mi = 0; mi < MF; mi++) {
            const int row = wr * (BM / 2) + mi * 16 + lr;
            af[mi] = *(const bf16x8*)(&sA[cur][row * 32 + (lg ^ ((row >> 1) & 3)) * 8]);
        }
#pragma unroll
        for (int ni = 0; ni < NF; ni++) {
            const int row = wc * (BN / 2) + ni * 16 + lr;
            bfr[ni] = *(const bf16x8*)(&sB[cur][row * 32 + (lg ^ ((row >> 1) & 3)) * 8]);
        }
#pragma unroll
        for (int mi = 0; mi < MF; mi++)
#pragma unroll
            for (int ni = 0; ni < NF; ni++)
                acc[mi][ni] = mfma16(af[mi], bfr[ni], acc[mi][ni]);
        cur ^= 1;
    }

#pragma unroll
    for (int mi = 0; mi < MF; mi++) {
        const int rbase = m0 + wr * (BM / 2) + mi * 16 + lg * 4;
#pragma unroll
        for (int ni = 0; ni < NF; ni++) {
            const int col = n0 + wc * (BN / 2) + ni * 16 + lr;
            const float* bp = b0; int cc = col;
            if (b1 && col >= 512)  { bp = b1; cc = col - 512; }
            if (b2 && col >= 1024) { bp = b2; cc = col - 1024; }
            const float bv = bp[cc];
#pragma unroll
            for (int rr = 0; rr < 4; rr++) {
                float v = acc[mi][ni][rr] + bv;
                if (relu) v = fmaxf(v, 0.f);
                if (Cf) Cf[(size_t)(rbase + rr) * N + col] = v;
                if (Cb) Cb[(size_t)(rbase + rr) * N + col] = f2b(v);
            }
        }
    }
}

// ---------- V transpose: [B*T, rs] bf16 (64-col slice) -> VT [B,H,64,1024] ----------
__global__ __launch_bounds__(256) void vt_k(const u16* __restrict__ V, int rs,
                                            u16* __restrict__ VT) {
    const int bh = blockIdx.x;           // b*8+h
    const int b = bh >> 3;
    const int h64 = (bh & 7) * 64;
    const int t0 = blockIdx.y * 64;
    __shared__ u16 s[64 * 65];
    const int tid = threadIdx.x;
#pragma unroll
    for (int i = 0; i < 16; i++) {
        int t = (tid >> 6) + i * 4;
        int d = tid & 63;
        s[d * 65 + t] = V[(size_t)(b * 1024 + t0 + t) * rs + h64 + d];
    }
    __syncthreads();
#pragma unroll
    for (int i = 0; i < 16; i++) {
        int d = (tid >> 6) + i * 4;
        int t = tid & 63;
        VT[(size_t)(bh * 64 + d) * 1024 + t0 + t] = s[d * 65 + t];
    }
}

// ---------- flash attention, 1 wave per (b,h, 16 q-rows), 32 keys/iter ----------
template <int CAUSAL>
__global__ __launch_bounds__(64) void attn_k(const u16* __restrict__ Q, int qrs,
                                             const u16* __restrict__ Kb, int krs,
                                             const u16* __restrict__ VT,
                                             const int* __restrict__ tokens,
                                             const signed char* __restrict__ km8,
                                             u16* __restrict__ O, int LK) {
    const int bh = blockIdx.x;
    const int b = bh >> 3;
    const int h64 = (bh & 7) * 64;
    const int qb = blockIdx.y;
    const int lane = threadIdx.x;
    const int lg = lane >> 4, lr = lane & 15;
    const float NEG = -3.402823466e38f;

    const u16* qrow = Q + (size_t)(b * 1024 + qb * 16 + lr) * qrs + h64 + lg * 8;
    const bf16x8 aq0 = *(const bf16x8*)(qrow);
    const bf16x8 aq1 = *(const bf16x8*)(qrow + 32);

    f32x4 o[4];
#pragma unroll
    for (int ni = 0; ni < 4; ni++) o[ni] = (f32x4){0.f, 0.f, 0.f, 0.f};
    float m_run[4], l_run[4];
#pragma unroll
    for (int rr = 0; rr < 4; rr++) { m_run[rr] = NEG; l_run[rr] = 0.f; }

    __shared__ u16 sP[16 * 32];
    const u16* vbase = VT + (size_t)bh * 64 * LK;

    auto body = [&](int k0) {
        f32x4 s[2];
#pragma unroll
        for (int c = 0; c < 2; c++) {
            const u16* krow =
                Kb + (size_t)(b * LK + k0 + c * 16 + lr) * krs + h64 + lg * 8;
            bf16x8 bk0 = *(const bf16x8*)(krow);
            bf16x8 bk1 = *(const bf16x8*)(krow + 32);
            f32x4 t = (f32x4){0.f, 0.f, 0.f, 0.f};
            t = mfma16(aq0, bk0, t);
            t = mfma16(aq1, bk1, t);
            s[c] = t;
        }
#pragma unroll
        for (int c = 0; c < 2; c++) {
            const int key = k0 + c * 16 + lr;
            bool mkey;
            if (CAUSAL) mkey = (tokens[b * LK + key] == 0);
            else        mkey = (km8[b * LK + key] != 0);
#pragma unroll
            for (int rr = 0; rr < 4; rr++) {
                float sv = s[c][rr] * 0.125f;   // 1/sqrt(64)
                bool mk = mkey;
                if (CAUSAL) mk = mk || (key > qb * 16 + lg * 4 + rr);
                s[c][rr] = mk ? NEG : sv;
            }
        }
        float pf[4];
#pragma unroll
        for (int rr = 0; rr < 4; rr++) {
            float bm = fmaxf(s[0][rr], s[1][rr]);
            bm = fmaxf(bm, __shfl_xor(bm, 1));
            bm = fmaxf(bm, __shfl_xor(bm, 2));
            bm = fmaxf(bm, __shfl_xor(bm, 4));
            bm = fmaxf(bm, __shfl_xor(bm, 8));
            float mn = fmaxf(m_run[rr], bm);
            float sc = __expf(m_run[rr] - mn);
            float p0 = __expf(s[0][rr] - mn);
            float p1 = __expf(s[1][rr] - mn);
            float bs = p0 + p1;
            bs += __shfl_xor(bs, 1);
            bs += __shfl_xor(bs, 2);
            bs += __shfl_xor(bs, 4);
            bs += __shfl_xor(bs, 8);
            l_run[rr] = l_run[rr] * sc + bs;
            m_run[rr] = mn;
            pf[rr] = sc;
            s[0][rr] = p0; s[1][rr] = p1;
        }
#pragma unroll
        for (int ni = 0; ni < 4; ni++)
#pragma unroll
            for (int rr = 0; rr < 4; rr++) o[ni][rr] *= pf[rr];
        __syncthreads();
#pragma unroll
        for (int c = 0; c < 2; c++)
#pragma unroll
            for (int rr = 0; rr < 4; rr++)
                sP[(lg * 4 + rr) * 32 + c * 16 + lr] = f2b(s[c][rr]);
        __syncthreads();
        bf16x8 ap = *(const bf16x8*)(sP + lr * 32 + lg * 8);
#pragma unroll
        for (int ni = 0; ni < 4; ni++) {
            bf16x8 bv =
                *(const bf16x8*)(vbase + (size_t)(ni * 16 + lr) * LK + k0 + lg * 8);
            o[ni] = mfma16(ap, bv, o[ni]);
        }
    };

    int kend = CAUSAL ? (((qb * 16 + 15) >> 5) + 1) * 32 : LK;
    if (kend > LK) kend = LK;
    for (int k0 = 0; k0 < kend; k0 += 32) body(k0);
    if (CAUSAL && kend < LK) {
        bool fm = (m_run[0] == NEG) || (m_run[1] == NEG) ||
                  (m_run[2] == NEG) || (m_run[3] == NEG);
        if (__any(fm))
            for (int k0 = kend; k0 < LK; k0 += 32) body(k0);
    }

#pragma unroll
    for (int ni = 0; ni < 4; ni++)
#pragma unroll
        for (int rr = 0; rr < 4; rr++) {
            float v = o[ni][rr] / l_run[rr];
            O[(size_t)(b * 1024 + qb * 16 + lg * 4 + rr) * 512 + h64 + ni * 16 + lr] =
                f2b(v);
        }
}

// ---------- fused residual + LayerNorm; writes f32 (opt) + bf16 ----------
__global__ __launch_bounds__(256) void ln_k(const float* __restrict__ a,
                                            const float* __restrict__ res,
                                            const float* __restrict__ g,
                                            const float* __restrict__ be,
                                            float* __restrict__ outf,
                                            u16* __restrict__ outb) {
    const int row = blockIdx.x;
    const int tid = threadIdx.x;
    const size_t base = (size_t)row * 512;
    float2 av = ((const float2*)(a + base))[tid];
    float2 rv = ((const float2*)(res + base))[tid];
    float x0 = av.x + rv.x;
    float x1 = av.y + rv.y;
    float s = x0 + x1, q = x0 * x0 + x1 * x1;
#pragma unroll
    for (int off = 1; off < 64; off <<= 1) {
        s += __shfl_xor(s, off);
        q += __shfl_xor(q, off);
    }
    __shared__ float ps[8];
    const int wid = tid >> 6;
    if ((tid & 63) == 0) { ps[wid] = s; ps[wid + 4] = q; }
    __syncthreads();
    s = ps[0] + ps[1] + ps[2] + ps[3];
    q = ps[4] + ps[5] + ps[6] + ps[7];
    const float mu = s * (1.f / 512.f);
    const float var = q * (1.f / 512.f) - mu * mu;
    const float inv = rsqrtf(var + 1e-5f);
    float2 gv = ((const float2*)g)[tid];
    float2 bv = ((const float2*)be)[tid];
    float y0 = gv.x * (x0 - mu) * inv + bv.x;
    float y1 = gv.y * (x1 - mu) * inv + bv.y;
    if (outf) { ((float2*)(outf + base))[tid] = make_float2(y0, y1); }
    outb[base + tid * 2] = f2b(y0);
    outb[base + tid * 2 + 1] = f2b(y1);
}

// ---------- host ----------
extern "C" void kernel_launch(void* const* d_in, const int* in_sizes, int n_in,
                              void* d_out, int out_size, void* d_ws, size_t ws_size,
                              hipStream_t stream) {
    (void)in_sizes; (void)n_in; (void)out_size;
    const int*   tokens  = (const int*)d_in[0];
    const float* enc     = (const float*)d_in[1];
    const signed char* encmask = (const signed char*)d_in[2];
    const float* emb     = (const float*)d_in[3];
    const float* Wq  = (const float*)d_in[4];  const float* bq  = (const float*)d_in[5];
    const float* Wk  = (const float*)d_in[6];  const float* bk  = (const float*)d_in[7];
    const float* Wv  = (const float*)d_in[8];  const float* bv  = (const float*)d_in[9];
    const float* Wo1 = (const float*)d_in[10]; const float* bo1 = (const float*)d_in[11];
    const float* cWq = (const float*)d_in[12]; const float* cbq = (const float*)d_in[13];
    const float* eWk = (const float*)d_in[14]; const float* ebk = (const float*)d_in[15];
    const float* eWv = (const float*)d_in[16]; const float* ebv = (const float*)d_in[17];
    const float* Wo2 = (const float*)d_in[18]; const float* bo2 = (const float*)d_in[19];
    const float* W1  = (const float*)d_in[20]; const float* b1  = (const float*)d_in[21];
    const float* W2  = (const float*)d_in[22]; const float* b2  = (const float*)d_in[23];
    const float* g1  = (const float*)d_in[24]; const float* be1 = (const float*)d_in[25];
    const float* g2  = (const float*)d_in[26]; const float* be2 = (const float*)d_in[27];
    const float* g3  = (const float*)d_in[28]; const float* be3 = (const float*)d_in[29];
    const float* Wout= (const float*)d_in[30]; const float* bout= (const float*)d_in[31];
    float* out = (float*)d_out;

    char* ws = (char*)d_ws;
    size_t off = 0;
    auto alloc = [&](size_t bytes) -> void* {
        void* p = ws + off;
        off += (bytes + 255) & ~(size_t)255;
        return p;
    };

    u16* Wqkvb = (u16*)alloc((size_t)786432 * 2);        // [1536,512]
    u16* Wo1b  = (u16*)alloc(262144 * 2);
    u16* cWqb  = (u16*)alloc(262144 * 2);
    u16* eWkvb = (u16*)alloc((size_t)524288 * 2);        // [1024,512]
    u16* Wo2b  = (u16*)alloc(262144 * 2);
    u16* W1b   = (u16*)alloc(524288 * 2);
    u16* W2b   = (u16*)alloc(524288 * 2);
    u16* Woutb = (u16*)alloc((size_t)16384000 * 2);
    u16* encb  = (u16*)alloc((size_t)2097152 * 2);
    float* x0f = (float*)alloc((size_t)2097152 * 4);
    u16*   x0b = (u16*)alloc((size_t)2097152 * 2);
    float* x1f = (float*)alloc((size_t)2097152 * 4);
    u16*   x1b = (u16*)alloc((size_t)2097152 * 2);
    float* x2f = (float*)alloc((size_t)2097152 * 4);
    u16*   x2b = (u16*)alloc((size_t)2097152 * 2);
    u16*   x3b = (u16*)alloc((size_t)2097152 * 2);
    u16* qkv = (u16*)alloc((size_t)4096 * 1536 * 2);     // fused q|k|v
    u16* ekv = (u16*)alloc((size_t)4096 * 1024 * 2);     // fused ek|ev
    u16* cq  = (u16*)alloc((size_t)2097152 * 2);
    u16* vt  = (u16*)alloc((size_t)2097152 * 2);         // reused for both attns
    u16* t4  = (u16*)alloc((size_t)2097152 * 2);         // attn out (reused)
    float* p8 = (float*)alloc((size_t)2097152 * 4);
    u16*  hb  = (u16*)alloc((size_t)4194304 * 2);        // relu hidden [4096,1024]
    if (off > ws_size) return;

    // merged weight/enc casts (12 regions, one launch)
    CastArgs ca;
    const float* srcs[12] = {Wq, Wk, Wv, Wo1, cWq, eWk, eWv, Wo2, W1, W2, enc, Wout};
    u16* dsts[12] = {Wqkvb, Wqkvb + 262144, Wqkvb + 524288, Wo1b, cWqb,
                     eWkvb, eWkvb + 262144, Wo2b, W1b, W2b, encb, Woutb};
    int ns[12] = {262144, 262144, 262144, 262144, 262144, 262144, 262144, 262144,
                  524288, 524288, 2097152, 16384000};
    int acc4 = 0;
    for (int j = 0; j < 12; j++) {
        ca.src[j] = (const float4*)srcs[j];
        ca.dst[j] = (ushort4*)dsts[j];
        ca.start4[j] = acc4;
        acc4 += ns[j] / 4;
    }
    ca.start4[12] = acc4;
    cast_all_k<<<2048, 256, 0, stream>>>(ca);

    embed_k<<<4096, 256, 0, stream>>>(tokens, emb, x0f, x0b);

    auto gemm128 = [&](const u16* A, const u16* Wb, const float* bb0,
                       const float* bb1, const float* bb2, float* Cf, u16* Cb,
                       int M, int N, int K, int relu) {
        gemm_bt_k<128, 128><<<dim3(M / 128, N / 128), 256, 0, stream>>>(
            A, Wb, bb0, bb1, bb2, Cf, Cb, M, N, K, relu);
    };
    auto gemm64 = [&](const u16* A, const u16* Wb, const float* bb0, float* Cf,
                      u16* Cb, int M, int N, int K, int relu) {
        gemm_bt_k<128, 64><<<dim3(M / 128, N / 64), 256, 0, stream>>>(
            A, Wb, bb0, nullptr, nullptr, Cf, Cb, M, N, K, relu);
    };

    // self-attention block (fused QKV)
    gemm128(x0b, Wqkvb, bq, bk, bv, nullptr, qkv, 4096, 1536, 512, 0);
    vt_k<<<dim3(32, 16), 256, 0, stream>>>(qkv + 1024, 1536, vt);
    attn_k<1><<<dim3(32, 64), 64, 0, stream>>>(qkv, 1536, qkv + 512, 1536, vt,
                                               tokens, nullptr, t4, 1024);
    gemm64(t4, Wo1b, bo1, p8, nullptr, 4096, 512, 512, 0);
    ln_k<<<4096, 256, 0, stream>>>(p8, x0f, g1, be1, x1f, x1b);

    // cross-attention block (fused eK/eV)
    gemm128(encb, eWkvb, ebk, ebv, nullptr, nullptr, ekv, 4096, 1024, 512, 0);
    vt_k<<<dim3(32, 16), 256, 0, stream>>>(ekv + 512, 1024, vt);
    gemm64(x1b, cWqb, cbq, nullptr, cq, 4096, 512, 512, 0);
    attn_k<0><<<dim3(32, 64), 64, 0, stream>>>(cq, 512, ekv, 1024, vt,
                                               nullptr, encmask, t4, 1024);
    gemm64(t4, Wo2b, bo2, p8, nullptr, 4096, 512, 512, 0);
    ln_k<<<4096, 256, 0, stream>>>(p8, x1f, g3, be3, x2f, x2b);

    // FFN
    gemm128(x2b, W1b, b1, nullptr, nullptr, nullptr, hb, 4096, 1024, 512, 1);
    gemm64(hb, W2b, b2, p8, nullptr, 4096, 512, 1024, 0);
    ln_k<<<4096, 256, 0, stream>>>(p8, x2f, g2, be2, nullptr, x3b);

    // vocab projection
    gemm128(x3b, Woutb, bout, nullptr, nullptr, out, nullptr, 4096, 32000, 512, 0);
}

// Round 4
// 527.590 us; speedup vs baseline: 1.2594x; 1.1121x over previous
//
#include <hip/hip_runtime.h>

#define DEV __device__ __forceinline__

typedef unsigned short u16;
typedef __attribute__((ext_vector_type(8))) __bf16 bf16x8;
typedef __attribute__((ext_vector_type(4))) float f32x4;

// ---------- helpers ----------
DEV u16 f2b(float f) {                       // f32 -> bf16 bits, RNE
    unsigned u = __builtin_bit_cast(unsigned, f);
    unsigned r = u + 0x7fffu + ((u >> 16) & 1u);
    return (u16)(r >> 16);
}

DEV f32x4 mfma16(bf16x8 a, bf16x8 b, f32x4 c) {
    return __builtin_amdgcn_mfma_f32_16x16x32_bf16(a, b, c, 0, 0, 0);
}

#define GLOAD_LDS16(gp, lp)                                                       \
    __builtin_amdgcn_global_load_lds((__attribute__((address_space(1))) void*)(gp), \
                                     (__attribute__((address_space(3))) void*)(lp), \
                                     16, 0, 0)

// ---------- merged f32 -> bf16 cast over 12 regions ----------
struct CastArgs {
    const float4* src[12];
    ushort4* dst[12];
    int start4[13];   // cumulative float4 offsets; start4[12] = total
};

__global__ __launch_bounds__(256) void cast_all_k(CastArgs a) {
    const int total = a.start4[12];
    for (int i = blockIdx.x * 256 + threadIdx.x; i < total; i += gridDim.x * 256) {
        int j = 0;
#pragma unroll
        for (int t = 1; t < 12; t++) j += (i >= a.start4[t]) ? 1 : 0;
        const int loc = i - a.start4[j];
        float4 v = a.src[j][loc];
        ushort4 o;
        o.x = f2b(v.x); o.y = f2b(v.y); o.z = f2b(v.z); o.w = f2b(v.w);
        a.dst[j][loc] = o;
    }
}

// ---------- embedding + positional encoding ----------
__global__ __launch_bounds__(256) void embed_k(const int* __restrict__ tokens,
                                               const float* __restrict__ emb,
                                               float* __restrict__ xf,
                                               u16* __restrict__ xb) {
    int i   = blockIdx.x * 256 + threadIdx.x;   // pair index
    int row = i >> 8;                            // b*T + t
    int dp  = i & 255;                           // d pair: d0 = 2*dp
    int pos = row & 1023;                        // T = 1024
    int tok = tokens[row];
    const float* e = emb + (size_t)tok * 512 + dp * 2;
    float e0 = e[0] * 22.627416997969522f;       // sqrt(512)
    float e1 = e[1] * 22.627416997969522f;
    float freq = exp2f(-(float)dp * 0.05190512648262190f);  // 10000^(-2dp/512)
    float ang  = (float)pos * freq;
    float v0 = e0 + __sinf(ang);
    float v1 = e1 + __cosf(ang);
    size_t o = (size_t)row * 512 + dp * 2;
    xf[o] = v0; xf[o + 1] = v1;
    xb[o] = f2b(v0); xb[o + 1] = f2b(v1);
}

// ---------- 128x128 NT GEMM (2-phase dbuf) for the small projections ----------
template <int BM, int BN>
__global__ __launch_bounds__(256) void gemm_bt_k(const u16* __restrict__ A,
                                                 const u16* __restrict__ W,
                                                 const float* __restrict__ b0,
                                                 const float* __restrict__ b1,
                                                 const float* __restrict__ b2,
                                                 float* __restrict__ Cf,
                                                 u16* __restrict__ Cb,
                                                 int M, int N, int K, int relu) {
    constexpr int MF = BM / 32;
    constexpr int NF = BN / 32;
    constexpr int CH_A = BM * 4;
    constexpr int CH_TOT = (BM + BN) * 4;
    __shared__ u16 sA[2][BM * 32];
    __shared__ u16 sB[2][BN * 32];

    const int gx = gridDim.x;
    const int nwg = gx * gridDim.y;
    const int orig = blockIdx.y * gx + blockIdx.x;
    const int xcd = orig & 7, chnk = orig >> 3;
    const int q = nwg >> 3, r = nwg & 7;
    const int wgid = (xcd < r ? xcd * (q + 1) : r * (q + 1) + (xcd - r) * q) + chnk;
    const int m0 = (wgid % gx) * BM;
    const int n0 = (wgid / gx) * BN;

    const int tid  = threadIdx.x;
    const int lane = tid & 63;
    const int wid  = tid >> 6;
    const int wr = wid >> 1, wc = wid & 1;
    const int lg = lane >> 4, lr = lane & 15;

    f32x4 acc[MF][NF];
#pragma unroll
    for (int i = 0; i < MF; i++)
#pragma unroll
        for (int j = 0; j < NF; j++) acc[i][j] = (f32x4){0.f, 0.f, 0.f, 0.f};

    auto stage = [&](int buf, int k0) {
#pragma unroll
        for (int c = tid; c < CH_TOT; c += 256) {
            if (c < CH_A) {
                const int row = c >> 2, ch = c & 3;
                const int gch = ch ^ ((row >> 1) & 3);
                GLOAD_LDS16(A + (size_t)(m0 + row) * K + k0 + gch * 8,
                            &sA[buf][c * 8]);
            } else {
                const int cb = c - CH_A;
                const int row = cb >> 2, ch = cb & 3;
                const int gch = ch ^ ((row >> 1) & 3);
                GLOAD_LDS16(W + (size_t)(n0 + row) * K + k0 + gch * 8,
                            &sB[buf][cb * 8]);
            }
        }
    };

    const int nt = K >> 5;
    stage(0, 0);
    int cur = 0;
    for (int t = 0; t < nt; t++) {
        __syncthreads();
        if (t + 1 < nt) stage(cur ^ 1, (t + 1) << 5);
        bf16x8 af[MF], bfr[NF];
#pragma unroll
        for (int mi = 0; mi < MF; mi++) {
            const int row = wr * (BM / 2) + mi * 16 + lr;
            af[mi] = *(const bf16x8*)(&sA[cur][row * 32 + (lg ^ ((row >> 1) & 3)) * 8]);
        }
#pragma unroll
        for (int ni = 0; ni < NF; ni++) {
            const int row = wc * (BN / 2) + ni * 16 + lr;
            bfr[ni] = *(const bf16x8*)(&sB[cur][row * 32 + (lg ^ ((row >> 1) & 3)) * 8]);
        }
#pragma unroll
        for (int mi = 0; mi < MF; mi++)
#pragma unroll
            for (int ni = 0; ni < NF; ni++)
                acc[mi][ni] = mfma16(af[mi], bfr[ni], acc[mi][ni]);
        cur ^= 1;
    }

#pragma unroll
    for (int mi = 0; mi < MF; mi++) {
        const int rbase = m0 + wr * (BM / 2) + mi * 16 + lg * 4;
#pragma unroll
        for (int ni = 0; ni < NF; ni++) {
            const int col = n0 + wc * (BN / 2) + ni * 16 + lr;
            const float* bp = b0; int cc = col;
            if (b1 && col >= 512)  { bp = b1; cc = col - 512; }
            if (b2 && col >= 1024) { bp = b2; cc = col - 1024; }
            const float bv = bp[cc];
#pragma unroll
            for (int rr = 0; rr < 4; rr++) {
                float v = acc[mi][ni][rr] + bv;
                if (relu) v = fmaxf(v, 0.f);
                if (Cf) Cf[(size_t)(rbase + rr) * N + col] = v;
                if (Cb) Cb[(size_t)(rbase + rr) * N + col] = f2b(v);
            }
        }
    }
}

// ---------- 256x256 NT GEMM, 8 waves, BK=32 ring-4, counted vmcnt (Wout) ----------
// Deep pipeline: 3 K-tiles prefetched ahead; vmcnt(8) steady-state (never 0 in
// main loop); single s_barrier per K-step. T2 XOR swizzle; T5 setprio on MFMA.
__global__ __launch_bounds__(512, 2) void gemm256_k(const u16* __restrict__ A,
                                                    const u16* __restrict__ W,
                                                    const float* __restrict__ bias,
                                                    float* __restrict__ C,
                                                    int M, int N, int K) {
    extern __shared__ u16 lds[];               // 4 * (256*32) * 2 (A|B) u16
    u16* sA = lds;                             // [4][8192]
    u16* sB = lds + 4 * 8192;                  // [4][8192]

    const int gx = gridDim.x;
    const int nwg = gx * gridDim.y;
    const int orig = blockIdx.y * gx + blockIdx.x;
    const int xcd = orig & 7, chnk = orig >> 3;
    const int q = nwg >> 3, r = nwg & 7;
    const int wgid = (xcd < r ? xcd * (q + 1) : r * (q + 1) + (xcd - r) * q) + chnk;
    const int m0 = (wgid % gx) * 256;
    const int n0 = (wgid / gx) * 256;

    const int tid  = threadIdx.x;
    const int lane = tid & 63;
    const int wid  = tid >> 6;           // 8 waves: wm = wid>>2, wn = wid&3
    const int wm = wid >> 2, wn = wid & 3;
    const int lg = lane >> 4, lr = lane & 15;

    f32x4 acc[8][4];
#pragma unroll
    for (int i = 0; i < 8; i++)
#pragma unroll
        for (int j = 0; j < 4; j++) acc[i][j] = (f32x4){0.f, 0.f, 0.f, 0.f};

    auto stage = [&](int b, int kt) {
        const int k0 = kt << 5;
#pragma unroll
        for (int h = 0; h < 2; h++) {
            const int c = tid + h * 512;         // 1024 chunks per matrix
            const int row = c >> 2, ch = c & 3;
            const int gch = ch ^ ((row >> 1) & 3);
            GLOAD_LDS16(A + (size_t)(m0 + row) * K + k0 + gch * 8,
                        sA + b * 8192 + c * 8);
            GLOAD_LDS16(W + (size_t)(n0 + row) * K + k0 + gch * 8,
                        sB + b * 8192 + c * 8);
        }
    };

    const int NT = K >> 5;                      // requires NT >= 3
    stage(0, 0); stage(1, 1); stage(2, 2);

    for (int kt = 0; kt < NT; kt++) {
        // own-wave counted wait (stage kt = oldest), THEN barrier -> all waves'
        // stage-kt loads are in LDS. Never drains the pipeline to 0 mid-loop.
        if (kt + 2 < NT)      asm volatile("s_waitcnt vmcnt(8)" ::: "memory");
        else if (kt + 1 < NT) asm volatile("s_waitcnt vmcnt(4)" ::: "memory");
        else                  asm volatile("s_waitcnt vmcnt(0)" ::: "memory");
        __builtin_amdgcn_s_barrier();

        const int bsel = kt & 3;
        // prefetch 3 ahead; target buf (kt+3)&3 == (kt-1)&3, freed by the
        // barrier above (all waves consumed their kt-1 frags before it).
        if (kt + 3 < NT) stage((kt + 3) & 3, kt + 3);

        bf16x8 af[8], bfr[4];
#pragma unroll
        for (int mi = 0; mi < 8; mi++) {
            const int row = wm * 128 + mi * 16 + lr;
            af[mi] = *(const bf16x8*)(sA + bsel * 8192 + row * 32 +
                                      (lg ^ ((row >> 1) & 3)) * 8);
        }
#pragma unroll
        for (int ni = 0; ni < 4; ni++) {
            const int row = wn * 64 + ni * 16 + lr;
            bfr[ni] = *(const bf16x8*)(sB + bsel * 8192 + row * 32 +
                                       (lg ^ ((row >> 1) & 3)) * 8);
        }
        __builtin_amdgcn_s_setprio(1);
#pragma unroll
        for (int mi = 0; mi < 8; mi++)
#pragma unroll
            for (int ni = 0; ni < 4; ni++)
                acc[mi][ni] = mfma16(af[mi], bfr[ni], acc[mi][ni]);
        __builtin_amdgcn_s_setprio(0);
    }

#pragma unroll
    for (int mi = 0; mi < 8; mi++) {
        const int rbase = m0 + wm * 128 + mi * 16 + lg * 4;
#pragma unroll
        for (int ni = 0; ni < 4; ni++) {
            const int col = n0 + wn * 64 + ni * 16 + lr;
            const float bv = bias[col];
#pragma unroll
            for (int rr = 0; rr < 4; rr++)
                C[(size_t)(rbase + rr) * N + col] = acc[mi][ni][rr] + bv;
        }
    }
}

// ---------- V transpose: [B*T, rs] bf16 (64-col slice) -> VT [B,H,64,1024] ----------
__global__ __launch_bounds__(256) void vt_k(const u16* __restrict__ V, int rs,
                                            u16* __restrict__ VT) {
    const int bh = blockIdx.x;           // b*8+h
    const int b = bh >> 3;
    const int h64 = (bh & 7) * 64;
    const int t0 = blockIdx.y * 64;
    __shared__ u16 s[64 * 65];
    const int tid = threadIdx.x;
#pragma unroll
    for (int i = 0; i < 16; i++) {
        int t = (tid >> 6) + i * 4;
        int d = tid & 63;
        s[d * 65 + t] = V[(size_t)(b * 1024 + t0 + t) * rs + h64 + d];
    }
    __syncthreads();
#pragma unroll
    for (int i = 0; i < 16; i++) {
        int d = (tid >> 6) + i * 4;
        int t = tid & 63;
        VT[(size_t)(bh * 64 + d) * 1024 + t0 + t] = s[d * 65 + t];
    }
}

// ---------- flash attention, 1 wave per (b,h, 16 q-rows), 32 keys/iter ----------
template <int CAUSAL>
__global__ __launch_bounds__(64) void attn_k(const u16* __restrict__ Q, int qrs,
                                             const u16* __restrict__ Kb, int krs,
                                             const u16* __restrict__ VT,
                                             const int* __restrict__ tokens,
                                             const signed char* __restrict__ km8,
                                             u16* __restrict__ O, int LK) {
    const int bh = blockIdx.x;
    const int b = bh >> 3;
    const int h64 = (bh & 7) * 64;
    const int qb = blockIdx.y;
    const int lane = threadIdx.x;
    const int lg = lane >> 4, lr = lane & 15;
    const float NEG = -3.402823466e38f;

    const u16* qrow = Q + (size_t)(b * 1024 + qb * 16 + lr) * qrs + h64 + lg * 8;
    const bf16x8 aq0 = *(const bf16x8*)(qrow);
    const bf16x8 aq1 = *(const bf16x8*)(qrow + 32);

    f32x4 o[4];
#pragma unroll
    for (int ni = 0; ni < 4; ni++) o[ni] = (f32x4){0.f, 0.f, 0.f, 0.f};
    float m_run[4], l_run[4];
#pragma unroll
    for (int rr = 0; rr < 4; rr++) { m_run[rr] = NEG; l_run[rr] = 0.f; }

    __shared__ u16 sP[16 * 32];
    const u16* vbase = VT + (size_t)bh * 64 * LK;

    auto body = [&](int k0) {
        f32x4 s[2];
#pragma unroll
        for (int c = 0; c < 2; c++) {
            const u16* krow =
                Kb + (size_t)(b * LK + k0 + c * 16 + lr) * krs + h64 + lg * 8;
            bf16x8 bk0 = *(const bf16x8*)(krow);
            bf16x8 bk1 = *(const bf16x8*)(krow + 32);
            f32x4 t = (f32x4){0.f, 0.f, 0.f, 0.f};
            t = mfma16(aq0, bk0, t);
            t = mfma16(aq1, bk1, t);
            s[c] = t;
        }
#pragma unroll
        for (int c = 0; c < 2; c++) {
            const int key = k0 + c * 16 + lr;
            bool mkey;
            if (CAUSAL) mkey = (tokens[b * LK + key] == 0);
            else        mkey = (km8[b * LK + key] != 0);
#pragma unroll
            for (int rr = 0; rr < 4; rr++) {
                float sv = s[c][rr] * 0.125f;   // 1/sqrt(64)
                bool mk = mkey;
                if (CAUSAL) mk = mk || (key > qb * 16 + lg * 4 + rr);
                s[c][rr] = mk ? NEG : sv;
            }
        }
        float pf[4];
#pragma unroll
        for (int rr = 0; rr < 4; rr++) {
            float bm = fmaxf(s[0][rr], s[1][rr]);
            bm = fmaxf(bm, __shfl_xor(bm, 1));
            bm = fmaxf(bm, __shfl_xor(bm, 2));
            bm = fmaxf(bm, __shfl_xor(bm, 4));
            bm = fmaxf(bm, __shfl_xor(bm, 8));
            float mn = fmaxf(m_run[rr], bm);
            float sc = __expf(m_run[rr] - mn);
            float p0 = __expf(s[0][rr] - mn);
            float p1 = __expf(s[1][rr] - mn);
            float bs = p0 + p1;
            bs += __shfl_xor(bs, 1);
            bs += __shfl_xor(bs, 2);
            bs += __shfl_xor(bs, 4);
            bs += __shfl_xor(bs, 8);
            l_run[rr] = l_run[rr] * sc + bs;
            m_run[rr] = mn;
            pf[rr] = sc;
            s[0][rr] = p0; s[1][rr] = p1;
        }
#pragma unroll
        for (int ni = 0; ni < 4; ni++)
#pragma unroll
            for (int rr = 0; rr < 4; rr++) o[ni][rr] *= pf[rr];
        __syncthreads();
#pragma unroll
        for (int c = 0; c < 2; c++)
#pragma unroll
            for (int rr = 0; rr < 4; rr++)
                sP[(lg * 4 + rr) * 32 + c * 16 + lr] = f2b(s[c][rr]);
        __syncthreads();
        bf16x8 ap = *(const bf16x8*)(sP + lr * 32 + lg * 8);
#pragma unroll
        for (int ni = 0; ni < 4; ni++) {
            bf16x8 bv =
                *(const bf16x8*)(vbase + (size_t)(ni * 16 + lr) * LK + k0 + lg * 8);
            o[ni] = mfma16(ap, bv, o[ni]);
        }
    };

    int kend = CAUSAL ? (((qb * 16 + 15) >> 5) + 1) * 32 : LK;
    if (kend > LK) kend = LK;
    for (int k0 = 0; k0 < kend; k0 += 32) body(k0);
    if (CAUSAL && kend < LK) {
        bool fm = (m_run[0] == NEG) || (m_run[1] == NEG) ||
                  (m_run[2] == NEG) || (m_run[3] == NEG);
        if (__any(fm))
            for (int k0 = kend; k0 < LK; k0 += 32) body(k0);
    }

#pragma unroll
    for (int ni = 0; ni < 4; ni++)
#pragma unroll
        for (int rr = 0; rr < 4; rr++) {
            float v = o[ni][rr] / l_run[rr];
            O[(size_t)(b * 1024 + qb * 16 + lg * 4 + rr) * 512 + h64 + ni * 16 + lr] =
                f2b(v);
        }
}

// ---------- fused residual + LayerNorm; writes f32 (opt) + bf16 ----------
__global__ __launch_bounds__(256) void ln_k(const float* __restrict__ a,
                                            const float* __restrict__ res,
                                            const float* __restrict__ g,
                                            const float* __restrict__ be,
                                            float* __restrict__ outf,
                                            u16* __restrict__ outb) {
    const int row = blockIdx.x;
    const int tid = threadIdx.x;
    const size_t base = (size_t)row * 512;
    float2 av = ((const float2*)(a + base))[tid];
    float2 rv = ((const float2*)(res + base))[tid];
    float x0 = av.x + rv.x;
    float x1 = av.y + rv.y;
    float s = x0 + x1, q = x0 * x0 + x1 * x1;
#pragma unroll
    for (int off = 1; off < 64; off <<= 1) {
        s += __shfl_xor(s, off);
        q += __shfl_xor(q, off);
    }
    __shared__ float ps[8];
    const int wid = tid >> 6;
    if ((tid & 63) == 0) { ps[wid] = s; ps[wid + 4] = q; }
    __syncthreads();
    s = ps[0] + ps[1] + ps[2] + ps[3];
    q = ps[4] + ps[5] + ps[6] + ps[7];
    const float mu = s * (1.f / 512.f);
    const float var = q * (1.f / 512.f) - mu * mu;
    const float inv = rsqrtf(var + 1e-5f);
    float2 gv = ((const float2*)g)[tid];
    float2 bv = ((const float2*)be)[tid];
    float y0 = gv.x * (x0 - mu) * inv + bv.x;
    float y1 = gv.y * (x1 - mu) * inv + bv.y;
    if (outf) { ((float2*)(outf + base))[tid] = make_float2(y0, y1); }
    outb[base + tid * 2] = f2b(y0);
    outb[base + tid * 2 + 1] = f2b(y1);
}

// ---------- host ----------
extern "C" void kernel_launch(void* const* d_in, const int* in_sizes, int n_in,
                              void* d_out, int out_size, void* d_ws, size_t ws_size,
                              hipStream_t stream) {
    (void)in_sizes; (void)n_in; (void)out_size;
    const int*   tokens  = (const int*)d_in[0];
    const float* enc     = (const float*)d_in[1];
    const signed char* encmask = (const signed char*)d_in[2];
    const float* emb     = (const float*)d_in[3];
    const float* Wq  = (const float*)d_in[4];  const float* bq  = (const float*)d_in[5];
    const float* Wk  = (const float*)d_in[6];  const float* bk  = (const float*)d_in[7];
    const float* Wv  = (const float*)d_in[8];  const float* bv  = (const float*)d_in[9];
    const float* Wo1 = (const float*)d_in[10]; const float* bo1 = (const float*)d_in[11];
    const float* cWq = (const float*)d_in[12]; const float* cbq = (const float*)d_in[13];
    const float* eWk = (const float*)d_in[14]; const float* ebk = (const float*)d_in[15];
    const float* eWv = (const float*)d_in[16]; const float* ebv = (const float*)d_in[17];
    const float* Wo2 = (const float*)d_in[18]; const float* bo2 = (const float*)d_in[19];
    const float* W1  = (const float*)d_in[20]; const float* b1  = (const float*)d_in[21];
    const float* W2  = (const float*)d_in[22]; const float* b2  = (const float*)d_in[23];
    const float* g1  = (const float*)d_in[24]; const float* be1 = (const float*)d_in[25];
    const float* g2  = (const float*)d_in[26]; const float* be2 = (const float*)d_in[27];
    const float* g3  = (const float*)d_in[28]; const float* be3 = (const float*)d_in[29];
    const float* Wout= (const float*)d_in[30]; const float* bout= (const float*)d_in[31];
    float* out = (float*)d_out;

    char* ws = (char*)d_ws;
    size_t off = 0;
    auto alloc = [&](size_t bytes) -> void* {
        void* p = ws + off;
        off += (bytes + 255) & ~(size_t)255;
        return p;
    };

    u16* Wqkvb = (u16*)alloc((size_t)786432 * 2);        // [1536,512]
    u16* Wo1b  = (u16*)alloc(262144 * 2);
    u16* cWqb  = (u16*)alloc(262144 * 2);
    u16* eWkvb = (u16*)alloc((size_t)524288 * 2);        // [1024,512]
    u16* Wo2b  = (u16*)alloc(262144 * 2);
    u16* W1b   = (u16*)alloc(524288 * 2);
    u16* W2b   = (u16*)alloc(524288 * 2);
    u16* Woutb = (u16*)alloc((size_t)16384000 * 2);
    u16* encb  = (u16*)alloc((size_t)2097152 * 2);
    float* x0f = (float*)alloc((size_t)2097152 * 4);
    u16*   x0b = (u16*)alloc((size_t)2097152 * 2);
    float* x1f = (float*)alloc((size_t)2097152 * 4);
    u16*   x1b = (u16*)alloc((size_t)2097152 * 2);
    float* x2f = (float*)alloc((size_t)2097152 * 4);
    u16*   x2b = (u16*)alloc((size_t)2097152 * 2);
    u16*   x3b = (u16*)alloc((size_t)2097152 * 2);
    u16* qkv = (u16*)alloc((size_t)4096 * 1536 * 2);     // fused q|k|v
    u16* ekv = (u16*)alloc((size_t)4096 * 1024 * 2);     // fused ek|ev
    u16* cq  = (u16*)alloc((size_t)2097152 * 2);
    u16* vt  = (u16*)alloc((size_t)2097152 * 2);         // reused for both attns
    u16* t4  = (u16*)alloc((size_t)2097152 * 2);         // attn out (reused)
    float* p8 = (float*)alloc((size_t)2097152 * 4);
    u16*  hb  = (u16*)alloc((size_t)4194304 * 2);        // relu hidden [4096,1024]
    if (off > ws_size) return;

    // merged weight/enc casts (12 regions, one launch)
    CastArgs ca;
    const float* srcs[12] = {Wq, Wk, Wv, Wo1, cWq, eWk, eWv, Wo2, W1, W2, enc, Wout};
    u16* dsts[12] = {Wqkvb, Wqkvb + 262144, Wqkvb + 524288, Wo1b, cWqb,
                     eWkvb, eWkvb + 262144, Wo2b, W1b, W2b, encb, Woutb};
    int ns[12] = {262144, 262144, 262144, 262144, 262144, 262144, 262144, 262144,
                  524288, 524288, 2097152, 16384000};
    int acc4 = 0;
    for (int j = 0; j < 12; j++) {
        ca.src[j] = (const float4*)srcs[j];
        ca.dst[j] = (ushort4*)dsts[j];
        ca.start4[j] = acc4;
        acc4 += ns[j] / 4;
    }
    ca.start4[12] = acc4;
    cast_all_k<<<2048, 256, 0, stream>>>(ca);

    embed_k<<<4096, 256, 0, stream>>>(tokens, emb, x0f, x0b);

    auto gemm128 = [&](const u16* A, const u16* Wb, const float* bb0,
                       const float* bb1, const float* bb2, float* Cf, u16* Cb,
                       int M, int N, int K, int relu) {
        gemm_bt_k<128, 128><<<dim3(M / 128, N / 128), 256, 0, stream>>>(
            A, Wb, bb0, bb1, bb2, Cf, Cb, M, N, K, relu);
    };
    auto gemm64 = [&](const u16* A, const u16* Wb, const float* bb0, float* Cf,
                      u16* Cb, int M, int N, int K, int relu) {
        gemm_bt_k<128, 64><<<dim3(M / 128, N / 64), 256, 0, stream>>>(
            A, Wb, bb0, nullptr, nullptr, Cf, Cb, M, N, K, relu);
    };

    // self-attention block (fused QKV)
    gemm128(x0b, Wqkvb, bq, bk, bv, nullptr, qkv, 4096, 1536, 512, 0);
    vt_k<<<dim3(32, 16), 256, 0, stream>>>(qkv + 1024, 1536, vt);
    attn_k<1><<<dim3(32, 64), 64, 0, stream>>>(qkv, 1536, qkv + 512, 1536, vt,
                                               tokens, nullptr, t4, 1024);
    gemm64(t4, Wo1b, bo1, p8, nullptr, 4096, 512, 512, 0);
    ln_k<<<4096, 256, 0, stream>>>(p8, x0f, g1, be1, x1f, x1b);

    // cross-attention block (fused eK/eV)
    gemm128(encb, eWkvb, ebk, ebv, nullptr, nullptr, ekv, 4096, 1024, 512, 0);
    vt_k<<<dim3(32, 16), 256, 0, stream>>>(ekv + 512, 1024, vt);
    gemm64(x1b, cWqb, cbq, nullptr, cq, 4096, 512, 512, 0);
    attn_k<0><<<dim3(32, 64), 64, 0, stream>>>(cq, 512, ekv, 1024, vt,
                                               nullptr, encmask, t4, 1024);
    gemm64(t4, Wo2b, bo2, p8, nullptr, 4096, 512, 512, 0);
    ln_k<<<4096, 256, 0, stream>>>(p8, x1f, g3, be3, x2f, x2b);

    // FFN
    gemm128(x2b, W1b, b1, nullptr, nullptr, nullptr, hb, 4096, 1024, 512, 1);
    gemm64(hb, W2b, b2, p8, nullptr, 4096, 512, 1024, 0);
    ln_k<<<4096, 256, 0, stream>>>(p8, x2f, g2, be2, nullptr, x3b);

    // vocab projection: 256x256 deep-pipelined GEMM, 16x125 = 2000 blocks
    gemm256_k<<<dim3(16, 125), 512, 131072, stream>>>(x3b, Woutb, bout, out,
                                                      4096, 32000, 512);
}

// Round 5
// 505.666 us; speedup vs baseline: 1.3140x; 1.0434x over previous
//
#include <hip/hip_runtime.h>

#define DEV __device__ __forceinline__

typedef unsigned short u16;
typedef __attribute__((ext_vector_type(8))) __bf16 bf16x8;
typedef __attribute__((ext_vector_type(4))) float f32x4;

// ---------- helpers ----------
DEV u16 f2b(float f) {                       // f32 -> bf16 bits, RNE
    unsigned u = __builtin_bit_cast(unsigned, f);
    unsigned r = u + 0x7fffu + ((u >> 16) & 1u);
    return (u16)(r >> 16);
}

DEV f32x4 mfma16(bf16x8 a, bf16x8 b, f32x4 c) {
    return __builtin_amdgcn_mfma_f32_16x16x32_bf16(a, b, c, 0, 0, 0);
}

#define GLOAD_LDS16(gp, lp)                                                       \
    __builtin_amdgcn_global_load_lds((__attribute__((address_space(1))) void*)(gp), \
                                     (__attribute__((address_space(3))) void*)(lp), \
                                     16, 0, 0)

// counted waits for ring-4 pipelines (L = loads/thread/stage)
template <int L>
DEV void wait_ring(int kt, int NT) {
    if (kt + 2 < NT) {
        if constexpr (L == 2) asm volatile("s_waitcnt vmcnt(4)" ::: "memory");
        if constexpr (L == 3) asm volatile("s_waitcnt vmcnt(6)" ::: "memory");
        if constexpr (L == 4) asm volatile("s_waitcnt vmcnt(8)" ::: "memory");
    } else if (kt + 1 < NT) {
        if constexpr (L == 2) asm volatile("s_waitcnt vmcnt(2)" ::: "memory");
        if constexpr (L == 3) asm volatile("s_waitcnt vmcnt(3)" ::: "memory");
        if constexpr (L == 4) asm volatile("s_waitcnt vmcnt(4)" ::: "memory");
    } else {
        asm volatile("s_waitcnt vmcnt(0)" ::: "memory");
    }
}

// ---------- merged f32 -> bf16 cast over 12 regions ----------
struct CastArgs {
    const float4* src[12];
    ushort4* dst[12];
    int start4[13];
};

__global__ __launch_bounds__(256) void cast_all_k(CastArgs a) {
    const int total = a.start4[12];
    for (int i = blockIdx.x * 256 + threadIdx.x; i < total; i += gridDim.x * 256) {
        int j = 0;
#pragma unroll
        for (int t = 1; t < 12; t++) j += (i >= a.start4[t]) ? 1 : 0;
        const int loc = i - a.start4[j];
        float4 v = a.src[j][loc];
        ushort4 o;
        o.x = f2b(v.x); o.y = f2b(v.y); o.z = f2b(v.z); o.w = f2b(v.w);
        a.dst[j][loc] = o;
    }
}

// ---------- embedding + positional encoding ----------
__global__ __launch_bounds__(256) void embed_k(const int* __restrict__ tokens,
                                               const float* __restrict__ emb,
                                               float* __restrict__ xf,
                                               u16* __restrict__ xb) {
    int i   = blockIdx.x * 256 + threadIdx.x;
    int row = i >> 8;
    int dp  = i & 255;
    int pos = row & 1023;
    int tok = tokens[row];
    const float* e = emb + (size_t)tok * 512 + dp * 2;
    float e0 = e[0] * 22.627416997969522f;
    float e1 = e[1] * 22.627416997969522f;
    float freq = exp2f(-(float)dp * 0.05190512648262190f);
    float ang  = (float)pos * freq;
    float v0 = e0 + __sinf(ang);
    float v1 = e1 + __cosf(ang);
    size_t o = (size_t)row * 512 + dp * 2;
    xf[o] = v0; xf[o + 1] = v1;
    xb[o] = f2b(v0); xb[o + 1] = f2b(v1);
}

// ---------- small NT GEMM: BM=64 tiles, 4 waves, ring-4 + counted vmcnt ----------
template <int BM, int BN>
__global__ __launch_bounds__(256) void gemm_sm_k(const u16* __restrict__ A,
                                                 const u16* __restrict__ W,
                                                 const float* __restrict__ b0,
                                                 const float* __restrict__ b1,
                                                 const float* __restrict__ b2,
                                                 float* __restrict__ Cf,
                                                 u16* __restrict__ Cb,
                                                 int M, int N, int K, int relu) {
    constexpr int MF = BM / 32;
    constexpr int NF = BN / 32;
    constexpr int CH_A = BM * 4;
    constexpr int CH_TOT = (BM + BN) * 4;
    constexpr int L = CH_TOT / 256;
    __shared__ u16 sA[4][BM * 32];
    __shared__ u16 sB[4][BN * 32];

    const int gx = gridDim.x;
    const int nwg = gx * gridDim.y;
    const int orig = blockIdx.y * gx + blockIdx.x;
    const int xcd = orig & 7, chnk = orig >> 3;
    const int q = nwg >> 3, r = nwg & 7;
    const int wgid = (xcd < r ? xcd * (q + 1) : r * (q + 1) + (xcd - r) * q) + chnk;
    const int m0 = (wgid % gx) * BM;
    const int n0 = (wgid / gx) * BN;

    const int tid  = threadIdx.x;
    const int lane = tid & 63;
    const int wid  = tid >> 6;
    const int wr = wid >> 1, wc = wid & 1;
    const int lg = lane >> 4, lr = lane & 15;

    f32x4 acc[MF][NF];
#pragma unroll
    for (int i = 0; i < MF; i++)
#pragma unroll
        for (int j = 0; j < NF; j++) acc[i][j] = (f32x4){0.f, 0.f, 0.f, 0.f};

    auto stage = [&](int b, int kt) {
        const int k0 = kt << 5;
#pragma unroll
        for (int h = 0; h < L; h++) {
            const int c = tid + h * 256;
            if (c < CH_A) {
                const int row = c >> 2, ch = c & 3;
                const int gch = ch ^ ((row >> 1) & 3);
                GLOAD_LDS16(A + (size_t)(m0 + row) * K + k0 + gch * 8,
                            &sA[b][c * 8]);
            } else {
                const int cb = c - CH_A;
                const int row = cb >> 2, ch = cb & 3;
                const int gch = ch ^ ((row >> 1) & 3);
                GLOAD_LDS16(W + (size_t)(n0 + row) * K + k0 + gch * 8,
                            &sB[b][cb * 8]);
            }
        }
    };

    const int NT = K >> 5;
    stage(0, 0); stage(1, 1); stage(2, 2);

    for (int kt = 0; kt < NT; kt++) {
        wait_ring<L>(kt, NT);
        __builtin_amdgcn_s_barrier();
        const int bsel = kt & 3;
        if (kt + 3 < NT) stage((kt + 3) & 3, kt + 3);

        bf16x8 af[MF], bfr[NF];
#pragma unroll
        for (int mi = 0; mi < MF; mi++) {
            const int row = wr * (BM / 2) + mi * 16 + lr;
            af[mi] = *(const bf16x8*)(&sA[bsel][row * 32 + (lg ^ ((row >> 1) & 3)) * 8]);
        }
#pragma unroll
        for (int ni = 0; ni < NF; ni++) {
            const int row = wc * (BN / 2) + ni * 16 + lr;
            bfr[ni] = *(const bf16x8*)(&sB[bsel][row * 32 + (lg ^ ((row >> 1) & 3)) * 8]);
        }
        __builtin_amdgcn_s_setprio(1);
#pragma unroll
        for (int mi = 0; mi < MF; mi++)
#pragma unroll
            for (int ni = 0; ni < NF; ni++)
                acc[mi][ni] = mfma16(af[mi], bfr[ni], acc[mi][ni]);
        __builtin_amdgcn_s_setprio(0);
    }

#pragma unroll
    for (int mi = 0; mi < MF; mi++) {
        const int rbase = m0 + wr * (BM / 2) + mi * 16 + lg * 4;
#pragma unroll
        for (int ni = 0; ni < NF; ni++) {
            const int col = n0 + wc * (BN / 2) + ni * 16 + lr;
            const float* bp = b0; int cc = col;
            if (b1 && col >= 512)  { bp = b1; cc = col - 512; }
            if (b2 && col >= 1024) { bp = b2; cc = col - 1024; }
            const float bv = bp[cc];
#pragma unroll
            for (int rr = 0; rr < 4; rr++) {
                float v = acc[mi][ni][rr] + bv;
                if (relu) v = fmaxf(v, 0.f);
                if (Cf) Cf[(size_t)(rbase + rr) * N + col] = v;
                if (Cb) Cb[(size_t)(rbase + rr) * N + col] = f2b(v);
            }
        }
    }
}

// ---------- dual GEMM: z=0 QKV (N=1536), z=1 eKV (N=1024); BM=64,BN=128,K=512 ----------
struct DualArgs {
    const u16 *A0, *W0, *A1, *W1;
    const float *b00, *b01, *b02, *b10, *b11;
    u16 *C0, *C1;
};

__global__ __launch_bounds__(256) void gemm_dual_k(DualArgs da) {
    constexpr int BM = 64, BN = 128, MF = 2, NF = 4;
    constexpr int CH_A = BM * 4, CH_TOT = (BM + BN) * 4, L = CH_TOT / 256;
    __shared__ u16 sA[4][BM * 32];
    __shared__ u16 sB[4][BN * 32];

    const int z = blockIdx.z;
    const int gy = z ? 8 : 12;
    if ((int)blockIdx.y >= gy) return;
    const int N = z ? 1024 : 1536;
    const u16* A = z ? da.A1 : da.A0;
    const u16* W = z ? da.W1 : da.W0;
    u16* C = z ? da.C1 : da.C0;
    const int K = 512;

    const int gx = gridDim.x;                 // 64
    const int nwg = gx * gy;
    const int orig = blockIdx.y * gx + blockIdx.x;
    const int xcd = orig & 7, chnk = orig >> 3;
    const int q = nwg >> 3, r = nwg & 7;
    const int wgid = (xcd < r ? xcd * (q + 1) : r * (q + 1) + (xcd - r) * q) + chnk;
    const int m0 = (wgid % gx) * BM;
    const int n0 = (wgid / gx) * BN;

    const int tid  = threadIdx.x;
    const int lane = tid & 63;
    const int wid  = tid >> 6;
    const int wr = wid >> 1, wc = wid & 1;
    const int lg = lane >> 4, lr = lane & 15;

    f32x4 acc[MF][NF];
#pragma unroll
    for (int i = 0; i < MF; i++)
#pragma unroll
        for (int j = 0; j < NF; j++) acc[i][j] = (f32x4){0.f, 0.f, 0.f, 0.f};

    auto stage = [&](int b, int kt) {
        const int k0 = kt << 5;
#pragma unroll
        for (int h = 0; h < L; h++) {
            const int c = tid + h * 256;
            if (c < CH_A) {
                const int row = c >> 2, ch = c & 3;
                const int gch = ch ^ ((row >> 1) & 3);
                GLOAD_LDS16(A + (size_t)(m0 + row) * K + k0 + gch * 8,
                            &sA[b][c * 8]);
            } else {
                const int cb = c - CH_A;
                const int row = cb >> 2, ch = cb & 3;
                const int gch = ch ^ ((row >> 1) & 3);
                GLOAD_LDS16(W + (size_t)(n0 + row) * K + k0 + gch * 8,
                            &sB[b][cb * 8]);
            }
        }
    };

    const int NT = K >> 5;                    // 16
    stage(0, 0); stage(1, 1); stage(2, 2);

    for (int kt = 0; kt < NT; kt++) {
        wait_ring<L>(kt, NT);
        __builtin_amdgcn_s_barrier();
        const int bsel = kt & 3;
        if (kt + 3 < NT) stage((kt + 3) & 3, kt + 3);

        bf16x8 af[MF], bfr[NF];
#pragma unroll
        for (int mi = 0; mi < MF; mi++) {
            const int row = wr * (BM / 2) + mi * 16 + lr;
            af[mi] = *(const bf16x8*)(&sA[bsel][row * 32 + (lg ^ ((row >> 1) & 3)) * 8]);
        }
#pragma unroll
        for (int ni = 0; ni < NF; ni++) {
            const int row = wc * (BN / 2) + ni * 16 + lr;
            bfr[ni] = *(const bf16x8*)(&sB[bsel][row * 32 + (lg ^ ((row >> 1) & 3)) * 8]);
        }
        __builtin_amdgcn_s_setprio(1);
#pragma unroll
        for (int mi = 0; mi < MF; mi++)
#pragma unroll
            for (int ni = 0; ni < NF; ni++)
                acc[mi][ni] = mfma16(af[mi], bfr[ni], acc[mi][ni]);
        __builtin_amdgcn_s_setprio(0);
    }

#pragma unroll
    for (int mi = 0; mi < MF; mi++) {
        const int rbase = m0 + wr * (BM / 2) + mi * 16 + lg * 4;
#pragma unroll
        for (int ni = 0; ni < NF; ni++) {
            const int col = n0 + wc * (BN / 2) + ni * 16 + lr;
            const float* bp; int cc;
            if (z == 0) {
                if (col >= 1024)     { bp = da.b02; cc = col - 1024; }
                else if (col >= 512) { bp = da.b01; cc = col - 512; }
                else                 { bp = da.b00; cc = col; }
            } else {
                if (col >= 512)      { bp = da.b11; cc = col - 512; }
                else                 { bp = da.b10; cc = col; }
            }
            const float bv = bp[cc];
#pragma unroll
            for (int rr = 0; rr < 4; rr++)
                C[(size_t)(rbase + rr) * N + col] = f2b(acc[mi][ni][rr] + bv);
        }
    }
}

// ---------- 256x256 NT GEMM, 8 waves, ring-4, counted vmcnt (Wout) ----------
__global__ __launch_bounds__(512, 2) void gemm256_k(const u16* __restrict__ A,
                                                    const u16* __restrict__ W,
                                                    const float* __restrict__ bias,
                                                    float* __restrict__ C,
                                                    int M, int N, int K) {
    extern __shared__ u16 lds[];
    u16* sA = lds;                             // [4][8192]
    u16* sB = lds + 4 * 8192;                  // [4][8192]

    const int gx = gridDim.x;
    const int nwg = gx * gridDim.y;
    const int orig = blockIdx.y * gx + blockIdx.x;
    const int xcd = orig & 7, chnk = orig >> 3;
    const int q = nwg >> 3, r = nwg & 7;
    const int wgid = (xcd < r ? xcd * (q + 1) : r * (q + 1) + (xcd - r) * q) + chnk;
    const int m0 = (wgid % gx) * 256;
    const int n0 = (wgid / gx) * 256;

    const int tid  = threadIdx.x;
    const int lane = tid & 63;
    const int wid  = tid >> 6;
    const int wm = wid >> 2, wn = wid & 3;
    const int lg = lane >> 4, lr = lane & 15;

    f32x4 acc[8][4];
#pragma unroll
    for (int i = 0; i < 8; i++)
#pragma unroll
        for (int j = 0; j < 4; j++) acc[i][j] = (f32x4){0.f, 0.f, 0.f, 0.f};

    auto stage = [&](int b, int kt) {
        const int k0 = kt << 5;
#pragma unroll
        for (int h = 0; h < 2; h++) {
            const int c = tid + h * 512;
            const int row = c >> 2, ch = c & 3;
            const int gch = ch ^ ((row >> 1) & 3);
            GLOAD_LDS16(A + (size_t)(m0 + row) * K + k0 + gch * 8,
                        sA + b * 8192 + c * 8);
            GLOAD_LDS16(W + (size_t)(n0 + row) * K + k0 + gch * 8,
                        sB + b * 8192 + c * 8);
        }
    };

    const int NT = K >> 5;
    stage(0, 0); stage(1, 1); stage(2, 2);

    for (int kt = 0; kt < NT; kt++) {
        wait_ring<4>(kt, NT);
        __builtin_amdgcn_s_barrier();
        const int bsel = kt & 3;
        if (kt + 3 < NT) stage((kt + 3) & 3, kt + 3);

        bf16x8 af[8], bfr[4];
#pragma unroll
        for (int mi = 0; mi < 8; mi++) {
            const int row = wm * 128 + mi * 16 + lr;
            af[mi] = *(const bf16x8*)(sA + bsel * 8192 + row * 32 +
                                      (lg ^ ((row >> 1) & 3)) * 8);
        }
#pragma unroll
        for (int ni = 0; ni < 4; ni++) {
            const int row = wn * 64 + ni * 16 + lr;
            bfr[ni] = *(const bf16x8*)(sB + bsel * 8192 + row * 32 +
                                       (lg ^ ((row >> 1) & 3)) * 8);
        }
        __builtin_amdgcn_s_setprio(1);
#pragma unroll
        for (int mi = 0; mi < 8; mi++)
#pragma unroll
            for (int ni = 0; ni < 4; ni++)
                acc[mi][ni] = mfma16(af[mi], bfr[ni], acc[mi][ni]);
        __builtin_amdgcn_s_setprio(0);
    }

#pragma unroll
    for (int mi = 0; mi < 8; mi++) {
        const int rbase = m0 + wm * 128 + mi * 16 + lg * 4;
#pragma unroll
        for (int ni = 0; ni < 4; ni++) {
            const int col = n0 + wn * 64 + ni * 16 + lr;
            const float bv = bias[col];
#pragma unroll
            for (int rr = 0; rr < 4; rr++)
                C[(size_t)(rbase + rr) * N + col] = acc[mi][ni][rr] + bv;
        }
    }
}

// ---------- V transpose: [B*T, rs] bf16 (64-col slice) -> VT [B,H,64,1024] ----------
__global__ __launch_bounds__(256) void vt_k(const u16* __restrict__ V, int rs,
                                            u16* __restrict__ VT) {
    const int bh = blockIdx.x;
    const int b = bh >> 3;
    const int h64 = (bh & 7) * 64;
    const int t0 = blockIdx.y * 64;
    __shared__ u16 s[64 * 65];
    const int tid = threadIdx.x;
#pragma unroll
    for (int i = 0; i < 16; i++) {
        int t = (tid >> 6) + i * 4;
        int d = tid & 63;
        s[d * 65 + t] = V[(size_t)(b * 1024 + t0 + t) * rs + h64 + d];
    }
    __syncthreads();
#pragma unroll
    for (int i = 0; i < 16; i++) {
        int d = (tid >> 6) + i * 4;
        int t = tid & 63;
        VT[(size_t)(bh * 64 + d) * 1024 + t0 + t] = s[d * 65 + t];
    }
}

// ---------- flash attention, 1 wave per (b,h, 16 q-rows), 32 keys/iter ----------
template <int CAUSAL>
__global__ __launch_bounds__(64) void attn_k(const u16* __restrict__ Q, int qrs,
                                             const u16* __restrict__ Kb, int krs,
                                             const u16* __restrict__ VT,
                                             const int* __restrict__ tokens,
                                             const signed char* __restrict__ km8,
                                             u16* __restrict__ O, int LK) {
    const int bh = blockIdx.x;
    const int b = bh >> 3;
    const int h64 = (bh & 7) * 64;
    const int qb = blockIdx.y;
    const int lane = threadIdx.x;
    const int lg = lane >> 4, lr = lane & 15;
    const float NEG = -3.402823466e38f;

    const u16* qrow = Q + (size_t)(b * 1024 + qb * 16 + lr) * qrs + h64 + lg * 8;
    const bf16x8 aq0 = *(const bf16x8*)(qrow);
    const bf16x8 aq1 = *(const bf16x8*)(qrow + 32);

    f32x4 o[4];
#pragma unroll
    for (int ni = 0; ni < 4; ni++) o[ni] = (f32x4){0.f, 0.f, 0.f, 0.f};
    float m_run[4], l_run[4];
#pragma unroll
    for (int rr = 0; rr < 4; rr++) { m_run[rr] = NEG; l_run[rr] = 0.f; }

    __shared__ u16 sP[16 * 32];
    const u16* vbase = VT + (size_t)bh * 64 * LK;

    auto body = [&](int k0) {
        f32x4 s[2];
#pragma unroll
        for (int c = 0; c < 2; c++) {
            const u16* krow =
                Kb + (size_t)(b * LK + k0 + c * 16 + lr) * krs + h64 + lg * 8;
            bf16x8 bk0 = *(const bf16x8*)(krow);
            bf16x8 bk1 = *(const bf16x8*)(krow + 32);
            f32x4 t = (f32x4){0.f, 0.f, 0.f, 0.f};
            t = mfma16(aq0, bk0, t);
            t = mfma16(aq1, bk1, t);
            s[c] = t;
        }
#pragma unroll
        for (int c = 0; c < 2; c++) {
            const int key = k0 + c * 16 + lr;
            bool mkey;
            if (CAUSAL) mkey = (tokens[b * LK + key] == 0);
            else        mkey = (km8[b * LK + key] != 0);
#pragma unroll
            for (int rr = 0; rr < 4; rr++) {
                float sv = s[c][rr] * 0.125f;
                bool mk = mkey;
                if (CAUSAL) mk = mk || (key > qb * 16 + lg * 4 + rr);
                s[c][rr] = mk ? NEG : sv;
            }
        }
        float pf[4];
#pragma unroll
        for (int rr = 0; rr < 4; rr++) {
            float bm = fmaxf(s[0][rr], s[1][rr]);
            bm = fmaxf(bm, __shfl_xor(bm, 1));
            bm = fmaxf(bm, __shfl_xor(bm, 2));
            bm = fmaxf(bm, __shfl_xor(bm, 4));
            bm = fmaxf(bm, __shfl_xor(bm, 8));
            float mn = fmaxf(m_run[rr], bm);
            float sc = __expf(m_run[rr] - mn);
            float p0 = __expf(s[0][rr] - mn);
            float p1 = __expf(s[1][rr] - mn);
            float bs = p0 + p1;
            bs += __shfl_xor(bs, 1);
            bs += __shfl_xor(bs, 2);
            bs += __shfl_xor(bs, 4);
            bs += __shfl_xor(bs, 8);
            l_run[rr] = l_run[rr] * sc + bs;
            m_run[rr] = mn;
            pf[rr] = sc;
            s[0][rr] = p0; s[1][rr] = p1;
        }
#pragma unroll
        for (int ni = 0; ni < 4; ni++)
#pragma unroll
            for (int rr = 0; rr < 4; rr++) o[ni][rr] *= pf[rr];
        __syncthreads();
#pragma unroll
        for (int c = 0; c < 2; c++)
#pragma unroll
            for (int rr = 0; rr < 4; rr++)
                sP[(lg * 4 + rr) * 32 + c * 16 + lr] = f2b(s[c][rr]);
        __syncthreads();
        bf16x8 ap = *(const bf16x8*)(sP + lr * 32 + lg * 8);
#pragma unroll
        for (int ni = 0; ni < 4; ni++) {
            bf16x8 bv =
                *(const bf16x8*)(vbase + (size_t)(ni * 16 + lr) * LK + k0 + lg * 8);
            o[ni] = mfma16(ap, bv, o[ni]);
        }
    };

    int kend = CAUSAL ? (((qb * 16 + 15) >> 5) + 1) * 32 : LK;
    if (kend > LK) kend = LK;
    for (int k0 = 0; k0 < kend; k0 += 32) body(k0);
    if (CAUSAL && kend < LK) {
        bool fm = (m_run[0] == NEG) || (m_run[1] == NEG) ||
                  (m_run[2] == NEG) || (m_run[3] == NEG);
        if (__any(fm))
            for (int k0 = kend; k0 < LK; k0 += 32) body(k0);
    }

#pragma unroll
    for (int ni = 0; ni < 4; ni++)
#pragma unroll
        for (int rr = 0; rr < 4; rr++) {
            float v = o[ni][rr] / l_run[rr];
            O[(size_t)(b * 1024 + qb * 16 + lg * 4 + rr) * 512 + h64 + ni * 16 + lr] =
                f2b(v);
        }
}

// ---------- fused residual + LayerNorm; writes f32 (opt) + bf16 ----------
__global__ __launch_bounds__(256) void ln_k(const float* __restrict__ a,
                                            const float* __restrict__ res,
                                            const float* __restrict__ g,
                                            const float* __restrict__ be,
                                            float* __restrict__ outf,
                                            u16* __restrict__ outb) {
    const int row = blockIdx.x;
    const int tid = threadIdx.x;
    const size_t base = (size_t)row * 512;
    float2 av = ((const float2*)(a + base))[tid];
    float2 rv = ((const float2*)(res + base))[tid];
    float x0 = av.x + rv.x;
    float x1 = av.y + rv.y;
    float s = x0 + x1, q = x0 * x0 + x1 * x1;
#pragma unroll
    for (int off = 1; off < 64; off <<= 1) {
        s += __shfl_xor(s, off);
        q += __shfl_xor(q, off);
    }
    __shared__ float ps[8];
    const int wid = tid >> 6;
    if ((tid & 63) == 0) { ps[wid] = s; ps[wid + 4] = q; }
    __syncthreads();
    s = ps[0] + ps[1] + ps[2] + ps[3];
    q = ps[4] + ps[5] + ps[6] + ps[7];
    const float mu = s * (1.f / 512.f);
    const float var = q * (1.f / 512.f) - mu * mu;
    const float inv = rsqrtf(var + 1e-5f);
    float2 gv = ((const float2*)g)[tid];
    float2 bv = ((const float2*)be)[tid];
    float y0 = gv.x * (x0 - mu) * inv + bv.x;
    float y1 = gv.y * (x1 - mu) * inv + bv.y;
    if (outf) { ((float2*)(outf + base))[tid] = make_float2(y0, y1); }
    outb[base + tid * 2] = f2b(y0);
    outb[base + tid * 2 + 1] = f2b(y1);
}

// ---------- host ----------
extern "C" void kernel_launch(void* const* d_in, const int* in_sizes, int n_in,
                              void* d_out, int out_size, void* d_ws, size_t ws_size,
                              hipStream_t stream) {
    (void)in_sizes; (void)n_in; (void)out_size;
    const int*   tokens  = (const int*)d_in[0];
    const float* enc     = (const float*)d_in[1];
    const signed char* encmask = (const signed char*)d_in[2];
    const float* emb     = (const float*)d_in[3];
    const float* Wq  = (const float*)d_in[4];  const float* bq  = (const float*)d_in[5];
    const float* Wk  = (const float*)d_in[6];  const float* bk  = (const float*)d_in[7];
    const float* Wv  = (const float*)d_in[8];  const float* bv  = (const float*)d_in[9];
    const float* Wo1 = (const float*)d_in[10]; const float* bo1 = (const float*)d_in[11];
    const float* cWq = (const float*)d_in[12]; const float* cbq = (const float*)d_in[13];
    const float* eWk = (const float*)d_in[14]; const float* ebk = (const float*)d_in[15];
    const float* eWv = (const float*)d_in[16]; const float* ebv = (const float*)d_in[17];
    const float* Wo2 = (const float*)d_in[18]; const float* bo2 = (const float*)d_in[19];
    const float* W1  = (const float*)d_in[20]; const float* b1  = (const float*)d_in[21];
    const float* W2  = (const float*)d_in[22]; const float* b2  = (const float*)d_in[23];
    const float* g1  = (const float*)d_in[24]; const float* be1 = (const float*)d_in[25];
    const float* g2  = (const float*)d_in[26]; const float* be2 = (const float*)d_in[27];
    const float* g3  = (const float*)d_in[28]; const float* be3 = (const float*)d_in[29];
    const float* Wout= (const float*)d_in[30]; const float* bout= (const float*)d_in[31];
    float* out = (float*)d_out;

    char* ws = (char*)d_ws;
    size_t off = 0;
    auto alloc = [&](size_t bytes) -> void* {
        void* p = ws + off;
        off += (bytes + 255) & ~(size_t)255;
        return p;
    };

    u16* Wqkvb = (u16*)alloc((size_t)786432 * 2);        // [1536,512]
    u16* Wo1b  = (u16*)alloc(262144 * 2);
    u16* cWqb  = (u16*)alloc(262144 * 2);
    u16* eWkvb = (u16*)alloc((size_t)524288 * 2);        // [1024,512]
    u16* Wo2b  = (u16*)alloc(262144 * 2);
    u16* W1b   = (u16*)alloc(524288 * 2);
    u16* W2b   = (u16*)alloc(524288 * 2);
    u16* Woutb = (u16*)alloc((size_t)16384000 * 2);
    u16* encb  = (u16*)alloc((size_t)2097152 * 2);
    float* x0f = (float*)alloc((size_t)2097152 * 4);
    u16*   x0b = (u16*)alloc((size_t)2097152 * 2);
    float* x1f = (float*)alloc((size_t)2097152 * 4);
    u16*   x1b = (u16*)alloc((size_t)2097152 * 2);
    float* x2f = (float*)alloc((size_t)2097152 * 4);
    u16*   x2b = (u16*)alloc((size_t)2097152 * 2);
    u16*   x3b = (u16*)alloc((size_t)2097152 * 2);
    u16* qkv = (u16*)alloc((size_t)4096 * 1536 * 2);     // fused q|k|v
    u16* ekv = (u16*)alloc((size_t)4096 * 1024 * 2);     // fused ek|ev
    u16* cq  = (u16*)alloc((size_t)2097152 * 2);
    u16* vt  = (u16*)alloc((size_t)2097152 * 2);         // self-attn VT
    u16* vt2 = (u16*)alloc((size_t)2097152 * 2);         // cross-attn VT
    u16* t4  = (u16*)alloc((size_t)2097152 * 2);         // attn out (reused)
    float* p8 = (float*)alloc((size_t)2097152 * 4);
    u16*  hb  = (u16*)alloc((size_t)4194304 * 2);        // relu hidden [4096,1024]
    if (off > ws_size) return;

    // merged weight/enc casts (12 regions, one launch)
    CastArgs ca;
    const float* srcs[12] = {Wq, Wk, Wv, Wo1, cWq, eWk, eWv, Wo2, W1, W2, enc, Wout};
    u16* dsts[12] = {Wqkvb, Wqkvb + 262144, Wqkvb + 524288, Wo1b, cWqb,
                     eWkvb, eWkvb + 262144, Wo2b, W1b, W2b, encb, Woutb};
    int ns[12] = {262144, 262144, 262144, 262144, 262144, 262144, 262144, 262144,
                  524288, 524288, 2097152, 16384000};
    int acc4 = 0;
    for (int j = 0; j < 12; j++) {
        ca.src[j] = (const float4*)srcs[j];
        ca.dst[j] = (ushort4*)dsts[j];
        ca.start4[j] = acc4;
        acc4 += ns[j] / 4;
    }
    ca.start4[12] = acc4;
    cast_all_k<<<2048, 256, 0, stream>>>(ca);

    embed_k<<<4096, 256, 0, stream>>>(tokens, emb, x0f, x0b);

    // fused QKV (x0b) + eKV (encb) in ONE launch
    DualArgs da;
    da.A0 = x0b;  da.W0 = Wqkvb; da.A1 = encb; da.W1 = eWkvb;
    da.b00 = bq;  da.b01 = bk;   da.b02 = bv;
    da.b10 = ebk; da.b11 = ebv;
    da.C0 = qkv;  da.C1 = ekv;
    gemm_dual_k<<<dim3(64, 12, 2), 256, 0, stream>>>(da);

    vt_k<<<dim3(32, 16), 256, 0, stream>>>(qkv + 1024, 1536, vt);
    vt_k<<<dim3(32, 16), 256, 0, stream>>>(ekv + 512, 1024, vt2);

    attn_k<1><<<dim3(32, 64), 64, 0, stream>>>(qkv, 1536, qkv + 512, 1536, vt,
                                               tokens, nullptr, t4, 1024);
    gemm_sm_k<64, 64><<<dim3(64, 8), 256, 0, stream>>>(
        t4, Wo1b, bo1, nullptr, nullptr, p8, nullptr, 4096, 512, 512, 0);
    ln_k<<<4096, 256, 0, stream>>>(p8, x0f, g1, be1, x1f, x1b);

    gemm_sm_k<64, 64><<<dim3(64, 8), 256, 0, stream>>>(
        x1b, cWqb, cbq, nullptr, nullptr, nullptr, cq, 4096, 512, 512, 0);
    attn_k<0><<<dim3(32, 64), 64, 0, stream>>>(cq, 512, ekv, 1024, vt2,
                                               nullptr, encmask, t4, 1024);
    gemm_sm_k<64, 64><<<dim3(64, 8), 256, 0, stream>>>(
        t4, Wo2b, bo2, nullptr, nullptr, p8, nullptr, 4096, 512, 512, 0);
    ln_k<<<4096, 256, 0, stream>>>(p8, x1f, g3, be3, x2f, x2b);

    // FFN
    gemm_sm_k<64, 128><<<dim3(64, 8), 256, 0, stream>>>(
        x2b, W1b, b1, nullptr, nullptr, nullptr, hb, 4096, 1024, 512, 1);
    gemm_sm_k<64, 64><<<dim3(64, 8), 256, 0, stream>>>(
        hb, W2b, b2, nullptr, nullptr, p8, nullptr, 4096, 512, 1024, 0);
    ln_k<<<4096, 256, 0, stream>>>(p8, x2f, g2, be2, nullptr, x3b);

    // vocab projection: 256x256 deep-pipelined GEMM, 16x125 = 2000 blocks
    gemm256_k<<<dim3(16, 125), 512, 131072, stream>>>(x3b, Woutb, bout, out,
                                                      4096, 32000, 512);
}

// Round 6
// 499.889 us; speedup vs baseline: 1.3292x; 1.0116x over previous
//
#include <hip/hip_runtime.h>

#define DEV __device__ __forceinline__

typedef unsigned short u16;
typedef __attribute__((ext_vector_type(8))) __bf16 bf16x8;
typedef __attribute__((ext_vector_type(4))) float f32x4;

// ---------- helpers ----------
DEV u16 f2b(float f) {                       // f32 -> bf16 bits, RNE
    unsigned u = __builtin_bit_cast(unsigned, f);
    unsigned r = u + 0x7fffu + ((u >> 16) & 1u);
    return (u16)(r >> 16);
}

DEV f32x4 mfma16(bf16x8 a, bf16x8 b, f32x4 c) {
    return __builtin_amdgcn_mfma_f32_16x16x32_bf16(a, b, c, 0, 0, 0);
}

#define GLOAD_LDS16(gp, lp)                                                       \
    __builtin_amdgcn_global_load_lds((__attribute__((address_space(1))) void*)(gp), \
                                     (__attribute__((address_space(3))) void*)(lp), \
                                     16, 0, 0)

// counted waits for ring-4 pipelines (L = loads/thread/stage)
template <int L>
DEV void wait_ring(int kt, int NT) {
    if (kt + 2 < NT) {
        if constexpr (L == 2) asm volatile("s_waitcnt vmcnt(4)" ::: "memory");
        if constexpr (L == 3) asm volatile("s_waitcnt vmcnt(6)" ::: "memory");
        if constexpr (L == 4) asm volatile("s_waitcnt vmcnt(8)" ::: "memory");
    } else if (kt + 1 < NT) {
        if constexpr (L == 2) asm volatile("s_waitcnt vmcnt(2)" ::: "memory");
        if constexpr (L == 3) asm volatile("s_waitcnt vmcnt(3)" ::: "memory");
        if constexpr (L == 4) asm volatile("s_waitcnt vmcnt(4)" ::: "memory");
    } else {
        asm volatile("s_waitcnt vmcnt(0)" ::: "memory");
    }
}

// ---------- merged f32 -> bf16 cast over 12 regions ----------
struct CastArgs {
    const float4* src[12];
    ushort4* dst[12];
    int start4[13];
};

__global__ __launch_bounds__(256) void cast_all_k(CastArgs a) {
    const int total = a.start4[12];
    for (int i = blockIdx.x * 256 + threadIdx.x; i < total; i += gridDim.x * 256) {
        int j = 0;
#pragma unroll
        for (int t = 1; t < 12; t++) j += (i >= a.start4[t]) ? 1 : 0;
        const int loc = i - a.start4[j];
        float4 v = a.src[j][loc];
        ushort4 o;
        o.x = f2b(v.x); o.y = f2b(v.y); o.z = f2b(v.z); o.w = f2b(v.w);
        a.dst[j][loc] = o;
    }
}

// ---------- embedding + positional encoding ----------
__global__ __launch_bounds__(256) void embed_k(const int* __restrict__ tokens,
                                               const float* __restrict__ emb,
                                               float* __restrict__ xf,
                                               u16* __restrict__ xb) {
    int i   = blockIdx.x * 256 + threadIdx.x;
    int row = i >> 8;
    int dp  = i & 255;
    int pos = row & 1023;
    int tok = tokens[row];
    const float* e = emb + (size_t)tok * 512 + dp * 2;
    float e0 = e[0] * 22.627416997969522f;
    float e1 = e[1] * 22.627416997969522f;
    float freq = exp2f(-(float)dp * 0.05190512648262190f);
    float ang  = (float)pos * freq;
    float v0 = e0 + __sinf(ang);
    float v1 = e1 + __cosf(ang);
    size_t o = (size_t)row * 512 + dp * 2;
    xf[o] = v0; xf[o + 1] = v1;
    xb[o] = f2b(v0); xb[o + 1] = f2b(v1);
}

// ---------- small NT GEMM: BM=64 tiles, 4 waves, ring-4 + counted vmcnt ----------
template <int BM, int BN>
__global__ __launch_bounds__(256) void gemm_sm_k(const u16* __restrict__ A,
                                                 const u16* __restrict__ W,
                                                 const float* __restrict__ b0,
                                                 const float* __restrict__ b1,
                                                 const float* __restrict__ b2,
                                                 float* __restrict__ Cf,
                                                 u16* __restrict__ Cb,
                                                 int M, int N, int K, int relu) {
    constexpr int MF = BM / 32;
    constexpr int NF = BN / 32;
    constexpr int CH_A = BM * 4;
    constexpr int CH_TOT = (BM + BN) * 4;
    constexpr int L = CH_TOT / 256;
    __shared__ u16 sA[4][BM * 32];
    __shared__ u16 sB[4][BN * 32];

    const int gx = gridDim.x;
    const int nwg = gx * gridDim.y;
    const int orig = blockIdx.y * gx + blockIdx.x;
    const int xcd = orig & 7, chnk = orig >> 3;
    const int q = nwg >> 3, r = nwg & 7;
    const int wgid = (xcd < r ? xcd * (q + 1) : r * (q + 1) + (xcd - r) * q) + chnk;
    const int m0 = (wgid % gx) * BM;
    const int n0 = (wgid / gx) * BN;

    const int tid  = threadIdx.x;
    const int lane = tid & 63;
    const int wid  = tid >> 6;
    const int wr = wid >> 1, wc = wid & 1;
    const int lg = lane >> 4, lr = lane & 15;

    f32x4 acc[MF][NF];
#pragma unroll
    for (int i = 0; i < MF; i++)
#pragma unroll
        for (int j = 0; j < NF; j++) acc[i][j] = (f32x4){0.f, 0.f, 0.f, 0.f};

    auto stage = [&](int b, int kt) {
        const int k0 = kt << 5;
#pragma unroll
        for (int h = 0; h < L; h++) {
            const int c = tid + h * 256;
            if (c < CH_A) {
                const int row = c >> 2, ch = c & 3;
                const int gch = ch ^ ((row >> 1) & 3);
                GLOAD_LDS16(A + (size_t)(m0 + row) * K + k0 + gch * 8,
                            &sA[b][c * 8]);
            } else {
                const int cb = c - CH_A;
                const int row = cb >> 2, ch = cb & 3;
                const int gch = ch ^ ((row >> 1) & 3);
                GLOAD_LDS16(W + (size_t)(n0 + row) * K + k0 + gch * 8,
                            &sB[b][cb * 8]);
            }
        }
    };

    const int NT = K >> 5;
    stage(0, 0); stage(1, 1); stage(2, 2);

    for (int kt = 0; kt < NT; kt++) {
        wait_ring<L>(kt, NT);
        __builtin_amdgcn_s_barrier();
        const int bsel = kt & 3;
        if (kt + 3 < NT) stage((kt + 3) & 3, kt + 3);

        bf16x8 af[MF], bfr[NF];
#pragma unroll
        for (int mi = 0; mi < MF; mi++) {
            const int row = wr * (BM / 2) + mi * 16 + lr;
            af[mi] = *(const bf16x8*)(&sA[bsel][row * 32 + (lg ^ ((row >> 1) & 3)) * 8]);
        }
#pragma unroll
        for (int ni = 0; ni < NF; ni++) {
            const int row = wc * (BN / 2) + ni * 16 + lr;
            bfr[ni] = *(const bf16x8*)(&sB[bsel][row * 32 + (lg ^ ((row >> 1) & 3)) * 8]);
        }
        __builtin_amdgcn_s_setprio(1);
#pragma unroll
        for (int mi = 0; mi < MF; mi++)
#pragma unroll
            for (int ni = 0; ni < NF; ni++)
                acc[mi][ni] = mfma16(af[mi], bfr[ni], acc[mi][ni]);
        __builtin_amdgcn_s_setprio(0);
    }

#pragma unroll
    for (int mi = 0; mi < MF; mi++) {
        const int rbase = m0 + wr * (BM / 2) + mi * 16 + lg * 4;
#pragma unroll
        for (int ni = 0; ni < NF; ni++) {
            const int col = n0 + wc * (BN / 2) + ni * 16 + lr;
            const float* bp = b0; int cc = col;
            if (b1 && col >= 512)  { bp = b1; cc = col - 512; }
            if (b2 && col >= 1024) { bp = b2; cc = col - 1024; }
            const float bv = bp[cc];
#pragma unroll
            for (int rr = 0; rr < 4; rr++) {
                float v = acc[mi][ni][rr] + bv;
                if (relu) v = fmaxf(v, 0.f);
                if (Cf) Cf[(size_t)(rbase + rr) * N + col] = v;
                if (Cb) Cb[(size_t)(rbase + rr) * N + col] = f2b(v);
            }
        }
    }
}

// ---------- dual GEMM: z=0 QKV (N=1536), z=1 eKV (N=1024); BM=64,BN=128,K=512 ----------
struct DualArgs {
    const u16 *A0, *W0, *A1, *W1;
    const float *b00, *b01, *b02, *b10, *b11;
    u16 *C0, *C1;
};

__global__ __launch_bounds__(256) void gemm_dual_k(DualArgs da) {
    constexpr int BM = 64, BN = 128, MF = 2, NF = 4;
    constexpr int CH_A = BM * 4, CH_TOT = (BM + BN) * 4, L = CH_TOT / 256;
    __shared__ u16 sA[4][BM * 32];
    __shared__ u16 sB[4][BN * 32];

    const int z = blockIdx.z;
    const int gy = z ? 8 : 12;
    if ((int)blockIdx.y >= gy) return;
    const int N = z ? 1024 : 1536;
    const u16* A = z ? da.A1 : da.A0;
    const u16* W = z ? da.W1 : da.W0;
    u16* C = z ? da.C1 : da.C0;
    const int K = 512;

    const int gx = gridDim.x;                 // 64
    const int nwg = gx * gy;
    const int orig = blockIdx.y * gx + blockIdx.x;
    const int xcd = orig & 7, chnk = orig >> 3;
    const int q = nwg >> 3, r = nwg & 7;
    const int wgid = (xcd < r ? xcd * (q + 1) : r * (q + 1) + (xcd - r) * q) + chnk;
    const int m0 = (wgid % gx) * BM;
    const int n0 = (wgid / gx) * BN;

    const int tid  = threadIdx.x;
    const int lane = tid & 63;
    const int wid  = tid >> 6;
    const int wr = wid >> 1, wc = wid & 1;
    const int lg = lane >> 4, lr = lane & 15;

    f32x4 acc[MF][NF];
#pragma unroll
    for (int i = 0; i < MF; i++)
#pragma unroll
        for (int j = 0; j < NF; j++) acc[i][j] = (f32x4){0.f, 0.f, 0.f, 0.f};

    auto stage = [&](int b, int kt) {
        const int k0 = kt << 5;
#pragma unroll
        for (int h = 0; h < L; h++) {
            const int c = tid + h * 256;
            if (c < CH_A) {
                const int row = c >> 2, ch = c & 3;
                const int gch = ch ^ ((row >> 1) & 3);
                GLOAD_LDS16(A + (size_t)(m0 + row) * K + k0 + gch * 8,
                            &sA[b][c * 8]);
            } else {
                const int cb = c - CH_A;
                const int row = cb >> 2, ch = cb & 3;
                const int gch = ch ^ ((row >> 1) & 3);
                GLOAD_LDS16(W + (size_t)(n0 + row) * K + k0 + gch * 8,
                            &sB[b][cb * 8]);
            }
        }
    };

    const int NT = K >> 5;                    // 16
    stage(0, 0); stage(1, 1); stage(2, 2);

    for (int kt = 0; kt < NT; kt++) {
        wait_ring<L>(kt, NT);
        __builtin_amdgcn_s_barrier();
        const int bsel = kt & 3;
        if (kt + 3 < NT) stage((kt + 3) & 3, kt + 3);

        bf16x8 af[MF], bfr[NF];
#pragma unroll
        for (int mi = 0; mi < MF; mi++) {
            const int row = wr * (BM / 2) + mi * 16 + lr;
            af[mi] = *(const bf16x8*)(&sA[bsel][row * 32 + (lg ^ ((row >> 1) & 3)) * 8]);
        }
#pragma unroll
        for (int ni = 0; ni < NF; ni++) {
            const int row = wc * (BN / 2) + ni * 16 + lr;
            bfr[ni] = *(const bf16x8*)(&sB[bsel][row * 32 + (lg ^ ((row >> 1) & 3)) * 8]);
        }
        __builtin_amdgcn_s_setprio(1);
#pragma unroll
        for (int mi = 0; mi < MF; mi++)
#pragma unroll
            for (int ni = 0; ni < NF; ni++)
                acc[mi][ni] = mfma16(af[mi], bfr[ni], acc[mi][ni]);
        __builtin_amdgcn_s_setprio(0);
    }

#pragma unroll
    for (int mi = 0; mi < MF; mi++) {
        const int rbase = m0 + wr * (BM / 2) + mi * 16 + lg * 4;
#pragma unroll
        for (int ni = 0; ni < NF; ni++) {
            const int col = n0 + wc * (BN / 2) + ni * 16 + lr;
            const float* bp; int cc;
            if (z == 0) {
                if (col >= 1024)     { bp = da.b02; cc = col - 1024; }
                else if (col >= 512) { bp = da.b01; cc = col - 512; }
                else                 { bp = da.b00; cc = col; }
            } else {
                if (col >= 512)      { bp = da.b11; cc = col - 512; }
                else                 { bp = da.b10; cc = col; }
            }
            const float bv = bp[cc];
#pragma unroll
            for (int rr = 0; rr < 4; rr++)
                C[(size_t)(rbase + rr) * N + col] = f2b(acc[mi][ni][rr] + bv);
        }
    }
}

// ---------- 256x256 NT GEMM (Wout): BK=64, 2-buf, 4-phase interleave ----------
// m201-style 8-phase/2-Ktile schedule in plain HIP. Per K-tile (BK=64), two
// halves s in {0,1}; each half: [vmcnt(4); barrier] then 2 phases, each
// {ds_read frags; issue one 16KB stage unit of tile t+1; setprio(1); 16 MFMA}.
// Stage units in flight never drain to 0 mid-loop (T4). 1 barrier per half.
__global__ __launch_bounds__(512, 2) void gemm256_k(const u16* __restrict__ A,
                                                    const u16* __restrict__ W,
                                                    const float* __restrict__ bias,
                                                    float* __restrict__ C,
                                                    int M, int N, int K) {
    extern __shared__ u16 lds[];
    // per buffer (32768 u16): A_s0 [0,8192) A_s1 [8192,16384)
    //                         B_s0 [16384,24576) B_s1 [24576,32768)
    const int gx = gridDim.x;
    const int nwg = gx * gridDim.y;
    const int orig = blockIdx.y * gx + blockIdx.x;
    const int xcd = orig & 7, chnk = orig >> 3;
    const int q = nwg >> 3, r = nwg & 7;
    const int wgid = (xcd < r ? xcd * (q + 1) : r * (q + 1) + (xcd - r) * q) + chnk;
    const int m0 = (wgid % gx) * 256;
    const int n0 = (wgid / gx) * 256;

    const int tid  = threadIdx.x;
    const int lane = tid & 63;
    const int wid  = tid >> 6;
    const int wm = wid >> 2, wn = wid & 3;   // 2x4 waves, per-wave out 128x64
    const int lg = lane >> 4, lr = lane & 15;

    f32x4 acc[8][4];
#pragma unroll
    for (int i = 0; i < 8; i++)
#pragma unroll
        for (int j = 0; j < 4; j++) acc[i][j] = (f32x4){0.f, 0.f, 0.f, 0.f};

    // stage one unit: unit 0=A_s0, 1=B_s0, 2=A_s1, 3=B_s1 (2 gloads/thread)
    auto stageU = [&](int buf, int kt, int unit) {
        const u16* src = (unit & 1) ? W : A;
        const int base0 = (unit & 1) ? n0 : m0;
        const int s = unit >> 1;
        const int k0 = (kt << 6) + (s << 5);
        u16* dst = lds + buf * 32768 + ((unit & 1) ? 16384 : 0) + s * 8192;
#pragma unroll
        for (int h = 0; h < 2; h++) {
            const int c = tid + h * 512;             // 1024 chunks of 16B
            const int row = c >> 2, ch = c & 3;
            const int gch = ch ^ ((row >> 1) & 3);
            GLOAD_LDS16(src + (size_t)(base0 + row) * K + k0 + gch * 8, dst + c * 8);
        }
    };

    const int NT = K >> 6;                           // K=512 -> 8 tiles (>=2)
    stageU(0, 0, 0); stageU(0, 0, 1); stageU(0, 0, 2); stageU(0, 0, 3);

    for (int t = 0; t < NT; t++) {
        const int buf = t & 1, nbuf = buf ^ 1;
        const bool more = (t + 1 < NT);
        const u16* aB = lds + buf * 32768;           // A sub-tiles base
        const u16* bB = lds + buf * 32768 + 16384;   // B sub-tiles base
#pragma unroll
        for (int s = 0; s < 2; s++) {
            // A_s(t),B_s(t) are the 2 oldest outstanding units (4 loads newer)
            if (s == 0 || more) asm volatile("s_waitcnt vmcnt(4)" ::: "memory");
            else                asm volatile("s_waitcnt vmcnt(0)" ::: "memory");
            __builtin_amdgcn_s_barrier();

            bf16x8 bfr[4];
#pragma unroll
            for (int ni = 0; ni < 4; ni++) {
                const int row = wn * 64 + ni * 16 + lr;
                bfr[ni] = *(const bf16x8*)(bB + s * 8192 + row * 32 +
                                           (lg ^ ((row >> 1) & 3)) * 8);
            }
            // phase mh=0: mi 0..3
            {
                bf16x8 af[4];
#pragma unroll
                for (int mi = 0; mi < 4; mi++) {
                    const int row = wm * 128 + mi * 16 + lr;
                    af[mi] = *(const bf16x8*)(aB + s * 8192 + row * 32 +
                                              (lg ^ ((row >> 1) & 3)) * 8);
                }
                if (more) stageU(nbuf, t + 1, s * 2);        // A_s(t+1)
                __builtin_amdgcn_s_setprio(1);
#pragma unroll
                for (int mi = 0; mi < 4; mi++)
#pragma unroll
                    for (int ni = 0; ni < 4; ni++)
                        acc[mi][ni] = mfma16(af[mi], bfr[ni], acc[mi][ni]);
                __builtin_amdgcn_s_setprio(0);
            }
            // phase mh=1: mi 4..7
            {
                bf16x8 af[4];
#pragma unroll
                for (int mi = 0; mi < 4; mi++) {
                    const int row = wm * 128 + (mi + 4) * 16 + lr;
                    af[mi] = *(const bf16x8*)(aB + s * 8192 + row * 32 +
                                              (lg ^ ((row >> 1) & 3)) * 8);
                }
                if (more) stageU(nbuf, t + 1, s * 2 + 1);    // B_s(t+1)
                __builtin_amdgcn_s_setprio(1);
#pragma unroll
                for (int mi = 0; mi < 4; mi++)
#pragma unroll
                    for (int ni = 0; ni < 4; ni++)
                        acc[mi + 4][ni] = mfma16(af[mi], bfr[ni], acc[mi + 4][ni]);
                __builtin_amdgcn_s_setprio(0);
            }
        }
    }

#pragma unroll
    for (int mi = 0; mi < 8; mi++) {
        const int rbase = m0 + wm * 128 + mi * 16 + lg * 4;
#pragma unroll
        for (int ni = 0; ni < 4; ni++) {
            const int col = n0 + wn * 64 + ni * 16 + lr;
            const float bv = bias[col];
#pragma unroll
            for (int rr = 0; rr < 4; rr++)
                C[(size_t)(rbase + rr) * N + col] = acc[mi][ni][rr] + bv;
        }
    }
}

// ---------- V transpose (both attns in one launch): z selects src ----------
__global__ __launch_bounds__(256) void vt_k(const u16* __restrict__ V0, int rs0,
                                            u16* __restrict__ VT0,
                                            const u16* __restrict__ V1, int rs1,
                                            u16* __restrict__ VT1) {
    const u16* V = blockIdx.z ? V1 : V0;
    u16* VT = blockIdx.z ? VT1 : VT0;
    const int rs = blockIdx.z ? rs1 : rs0;
    const int bh = blockIdx.x;
    const int b = bh >> 3;
    const int h64 = (bh & 7) * 64;
    const int t0 = blockIdx.y * 64;
    __shared__ u16 s[64 * 65];
    const int tid = threadIdx.x;
#pragma unroll
    for (int i = 0; i < 16; i++) {
        int t = (tid >> 6) + i * 4;
        int d = tid & 63;
        s[d * 65 + t] = V[(size_t)(b * 1024 + t0 + t) * rs + h64 + d];
    }
    __syncthreads();
#pragma unroll
    for (int i = 0; i < 16; i++) {
        int d = (tid >> 6) + i * 4;
        int t = tid & 63;
        VT[(size_t)(bh * 64 + d) * 1024 + t0 + t] = s[d * 65 + t];
    }
}

// ---------- flash attention, 1 wave per (b,h, 16 q-rows), 32 keys/iter ----------
template <int CAUSAL>
__global__ __launch_bounds__(64) void attn_k(const u16* __restrict__ Q, int qrs,
                                             const u16* __restrict__ Kb, int krs,
                                             const u16* __restrict__ VT,
                                             const int* __restrict__ tokens,
                                             const signed char* __restrict__ km8,
                                             u16* __restrict__ O, int LK) {
    const int bh = blockIdx.x;
    const int b = bh >> 3;
    const int h64 = (bh & 7) * 64;
    const int qb = blockIdx.y;
    const int lane = threadIdx.x;
    const int lg = lane >> 4, lr = lane & 15;
    const float NEG = -3.402823466e38f;

    const u16* qrow = Q + (size_t)(b * 1024 + qb * 16 + lr) * qrs + h64 + lg * 8;
    const bf16x8 aq0 = *(const bf16x8*)(qrow);
    const bf16x8 aq1 = *(const bf16x8*)(qrow + 32);

    f32x4 o[4];
#pragma unroll
    for (int ni = 0; ni < 4; ni++) o[ni] = (f32x4){0.f, 0.f, 0.f, 0.f};
    float m_run[4], l_run[4];
#pragma unroll
    for (int rr = 0; rr < 4; rr++) { m_run[rr] = NEG; l_run[rr] = 0.f; }

    __shared__ u16 sP[16 * 32];
    const u16* vbase = VT + (size_t)bh * 64 * LK;

    auto body = [&](int k0) {
        f32x4 s[2];
#pragma unroll
        for (int c = 0; c < 2; c++) {
            const u16* krow =
                Kb + (size_t)(b * LK + k0 + c * 16 + lr) * krs + h64 + lg * 8;
            bf16x8 bk0 = *(const bf16x8*)(krow);
            bf16x8 bk1 = *(const bf16x8*)(krow + 32);
            f32x4 t = (f32x4){0.f, 0.f, 0.f, 0.f};
            t = mfma16(aq0, bk0, t);
            t = mfma16(aq1, bk1, t);
            s[c] = t;
        }
#pragma unroll
        for (int c = 0; c < 2; c++) {
            const int key = k0 + c * 16 + lr;
            bool mkey;
            if (CAUSAL) mkey = (tokens[b * LK + key] == 0);
            else        mkey = (km8[b * LK + key] != 0);
#pragma unroll
            for (int rr = 0; rr < 4; rr++) {
                float sv = s[c][rr] * 0.125f;
                bool mk = mkey;
                if (CAUSAL) mk = mk || (key > qb * 16 + lg * 4 + rr);
                s[c][rr] = mk ? NEG : sv;
            }
        }
        float pf[4];
#pragma unroll
        for (int rr = 0; rr < 4; rr++) {
            float bm = fmaxf(s[0][rr], s[1][rr]);
            bm = fmaxf(bm, __shfl_xor(bm, 1));
            bm = fmaxf(bm, __shfl_xor(bm, 2));
            bm = fmaxf(bm, __shfl_xor(bm, 4));
            bm = fmaxf(bm, __shfl_xor(bm, 8));
            float mn = fmaxf(m_run[rr], bm);
            float sc = __expf(m_run[rr] - mn);
            float p0 = __expf(s[0][rr] - mn);
            float p1 = __expf(s[1][rr] - mn);
            float bs = p0 + p1;
            bs += __shfl_xor(bs, 1);
            bs += __shfl_xor(bs, 2);
            bs += __shfl_xor(bs, 4);
            bs += __shfl_xor(bs, 8);
            l_run[rr] = l_run[rr] * sc + bs;
            m_run[rr] = mn;
            pf[rr] = sc;
            s[0][rr] = p0; s[1][rr] = p1;
        }
#pragma unroll
        for (int ni = 0; ni < 4; ni++)
#pragma unroll
            for (int rr = 0; rr < 4; rr++) o[ni][rr] *= pf[rr];
        __syncthreads();
#pragma unroll
        for (int c = 0; c < 2; c++)
#pragma unroll
            for (int rr = 0; rr < 4; rr++)
                sP[(lg * 4 + rr) * 32 + c * 16 + lr] = f2b(s[c][rr]);
        __syncthreads();
        bf16x8 ap = *(const bf16x8*)(sP + lr * 32 + lg * 8);
#pragma unroll
        for (int ni = 0; ni < 4; ni++) {
            bf16x8 bv =
                *(const bf16x8*)(vbase + (size_t)(ni * 16 + lr) * LK + k0 + lg * 8);
            o[ni] = mfma16(ap, bv, o[ni]);
        }
    };

    int kend = CAUSAL ? (((qb * 16 + 15) >> 5) + 1) * 32 : LK;
    if (kend > LK) kend = LK;
    for (int k0 = 0; k0 < kend; k0 += 32) body(k0);
    if (CAUSAL && kend < LK) {
        bool fm = (m_run[0] == NEG) || (m_run[1] == NEG) ||
                  (m_run[2] == NEG) || (m_run[3] == NEG);
        if (__any(fm))
            for (int k0 = kend; k0 < LK; k0 += 32) body(k0);
    }

#pragma unroll
    for (int ni = 0; ni < 4; ni++)
#pragma unroll
        for (int rr = 0; rr < 4; rr++) {
            float v = o[ni][rr] / l_run[rr];
            O[(size_t)(b * 1024 + qb * 16 + lg * 4 + rr) * 512 + h64 + ni * 16 + lr] =
                f2b(v);
        }
}

// ---------- fused residual + LayerNorm; writes f32 (opt) + bf16 ----------
__global__ __launch_bounds__(256) void ln_k(const float* __restrict__ a,
                                            const float* __restrict__ res,
                                            const float* __restrict__ g,
                                            const float* __restrict__ be,
                                            float* __restrict__ outf,
                                            u16* __restrict__ outb) {
    const int row = blockIdx.x;
    const int tid = threadIdx.x;
    const size_t base = (size_t)row * 512;
    float2 av = ((const float2*)(a + base))[tid];
    float2 rv = ((const float2*)(res + base))[tid];
    float x0 = av.x + rv.x;
    float x1 = av.y + rv.y;
    float s = x0 + x1, q = x0 * x0 + x1 * x1;
#pragma unroll
    for (int off = 1; off < 64; off <<= 1) {
        s += __shfl_xor(s, off);
        q += __shfl_xor(q, off);
    }
    __shared__ float ps[8];
    const int wid = tid >> 6;
    if ((tid & 63) == 0) { ps[wid] = s; ps[wid + 4] = q; }
    __syncthreads();
    s = ps[0] + ps[1] + ps[2] + ps[3];
    q = ps[4] + ps[5] + ps[6] + ps[7];
    const float mu = s * (1.f / 512.f);
    const float var = q * (1.f / 512.f) - mu * mu;
    const float inv = rsqrtf(var + 1e-5f);
    float2 gv = ((const float2*)g)[tid];
    float2 bv = ((const float2*)be)[tid];
    float y0 = gv.x * (x0 - mu) * inv + bv.x;
    float y1 = gv.y * (x1 - mu) * inv + bv.y;
    if (outf) { ((float2*)(outf + base))[tid] = make_float2(y0, y1); }
    outb[base + tid * 2] = f2b(y0);
    outb[base + tid * 2 + 1] = f2b(y1);
}

// ---------- host ----------
extern "C" void kernel_launch(void* const* d_in, const int* in_sizes, int n_in,
                              void* d_out, int out_size, void* d_ws, size_t ws_size,
                              hipStream_t stream) {
    (void)in_sizes; (void)n_in; (void)out_size;
    const int*   tokens  = (const int*)d_in[0];
    const float* enc     = (const float*)d_in[1];
    const signed char* encmask = (const signed char*)d_in[2];
    const float* emb     = (const float*)d_in[3];
    const float* Wq  = (const float*)d_in[4];  const float* bq  = (const float*)d_in[5];
    const float* Wk  = (const float*)d_in[6];  const float* bk  = (const float*)d_in[7];
    const float* Wv  = (const float*)d_in[8];  const float* bv  = (const float*)d_in[9];
    const float* Wo1 = (const float*)d_in[10]; const float* bo1 = (const float*)d_in[11];
    const float* cWq = (const float*)d_in[12]; const float* cbq = (const float*)d_in[13];
    const float* eWk = (const float*)d_in[14]; const float* ebk = (const float*)d_in[15];
    const float* eWv = (const float*)d_in[16]; const float* ebv = (const float*)d_in[17];
    const float* Wo2 = (const float*)d_in[18]; const float* bo2 = (const float*)d_in[19];
    const float* W1  = (const float*)d_in[20]; const float* b1  = (const float*)d_in[21];
    const float* W2  = (const float*)d_in[22]; const float* b2  = (const float*)d_in[23];
    const float* g1  = (const float*)d_in[24]; const float* be1 = (const float*)d_in[25];
    const float* g2  = (const float*)d_in[26]; const float* be2 = (const float*)d_in[27];
    const float* g3  = (const float*)d_in[28]; const float* be3 = (const float*)d_in[29];
    const float* Wout= (const float*)d_in[30]; const float* bout= (const float*)d_in[31];
    float* out = (float*)d_out;

    char* ws = (char*)d_ws;
    size_t off = 0;
    auto alloc = [&](size_t bytes) -> void* {
        void* p = ws + off;
        off += (bytes + 255) & ~(size_t)255;
        return p;
    };

    u16* Wqkvb = (u16*)alloc((size_t)786432 * 2);        // [1536,512]
    u16* Wo1b  = (u16*)alloc(262144 * 2);
    u16* cWqb  = (u16*)alloc(262144 * 2);
    u16* eWkvb = (u16*)alloc((size_t)524288 * 2);        // [1024,512]
    u16* Wo2b  = (u16*)alloc(262144 * 2);
    u16* W1b   = (u16*)alloc(524288 * 2);
    u16* W2b   = (u16*)alloc(524288 * 2);
    u16* Woutb = (u16*)alloc((size_t)16384000 * 2);
    u16* encb  = (u16*)alloc((size_t)2097152 * 2);
    float* x0f = (float*)alloc((size_t)2097152 * 4);
    u16*   x0b = (u16*)alloc((size_t)2097152 * 2);
    float* x1f = (float*)alloc((size_t)2097152 * 4);
    u16*   x1b = (u16*)alloc((size_t)2097152 * 2);
    float* x2f = (float*)alloc((size_t)2097152 * 4);
    u16*   x2b = (u16*)alloc((size_t)2097152 * 2);
    u16*   x3b = (u16*)alloc((size_t)2097152 * 2);
    u16* qkv = (u16*)alloc((size_t)4096 * 1536 * 2);     // fused q|k|v
    u16* ekv = (u16*)alloc((size_t)4096 * 1024 * 2);     // fused ek|ev
    u16* cq  = (u16*)alloc((size_t)2097152 * 2);
    u16* vt  = (u16*)alloc((size_t)2097152 * 2);         // self-attn VT
    u16* vt2 = (u16*)alloc((size_t)2097152 * 2);         // cross-attn VT
    u16* t4  = (u16*)alloc((size_t)2097152 * 2);         // attn out (reused)
    float* p8 = (float*)alloc((size_t)2097152 * 4);
    u16*  hb  = (u16*)alloc((size_t)4194304 * 2);        // relu hidden [4096,1024]
    if (off > ws_size) return;

    // merged weight/enc casts (12 regions, one launch)
    CastArgs ca;
    const float* srcs[12] = {Wq, Wk, Wv, Wo1, cWq, eWk, eWv, Wo2, W1, W2, enc, Wout};
    u16* dsts[12] = {Wqkvb, Wqkvb + 262144, Wqkvb + 524288, Wo1b, cWqb,
                     eWkvb, eWkvb + 262144, Wo2b, W1b, W2b, encb, Woutb};
    int ns[12] = {262144, 262144, 262144, 262144, 262144, 262144, 262144, 262144,
                  524288, 524288, 2097152, 16384000};
    int acc4 = 0;
    for (int j = 0; j < 12; j++) {
        ca.src[j] = (const float4*)srcs[j];
        ca.dst[j] = (ushort4*)dsts[j];
        ca.start4[j] = acc4;
        acc4 += ns[j] / 4;
    }
    ca.start4[12] = acc4;
    cast_all_k<<<2048, 256, 0, stream>>>(ca);

    embed_k<<<4096, 256, 0, stream>>>(tokens, emb, x0f, x0b);

    // fused QKV (x0b) + eKV (encb) in ONE launch
    DualArgs da;
    da.A0 = x0b;  da.W0 = Wqkvb; da.A1 = encb; da.W1 = eWkvb;
    da.b00 = bq;  da.b01 = bk;   da.b02 = bv;
    da.b10 = ebk; da.b11 = ebv;
    da.C0 = qkv;  da.C1 = ekv;
    gemm_dual_k<<<dim3(64, 12, 2), 256, 0, stream>>>(da);

    // both V transposes, one launch
    vt_k<<<dim3(32, 16, 2), 256, 0, stream>>>(qkv + 1024, 1536, vt,
                                              ekv + 512, 1024, vt2);

    attn_k<1><<<dim3(32, 64), 64, 0, stream>>>(qkv, 1536, qkv + 512, 1536, vt,
                                               tokens, nullptr, t4, 1024);
    gemm_sm_k<64, 64><<<dim3(64, 8), 256, 0, stream>>>(
        t4, Wo1b, bo1, nullptr, nullptr, p8, nullptr, 4096, 512, 512, 0);
    ln_k<<<4096, 256, 0, stream>>>(p8, x0f, g1, be1, x1f, x1b);

    gemm_sm_k<64, 64><<<dim3(64, 8), 256, 0, stream>>>(
        x1b, cWqb, cbq, nullptr, nullptr, nullptr, cq, 4096, 512, 512, 0);
    attn_k<0><<<dim3(32, 64), 64, 0, stream>>>(cq, 512, ekv, 1024, vt2,
                                               nullptr, encmask, t4, 1024);
    gemm_sm_k<64, 64><<<dim3(64, 8), 256, 0, stream>>>(
        t4, Wo2b, bo2, nullptr, nullptr, p8, nullptr, 4096, 512, 512, 0);
    ln_k<<<4096, 256, 0, stream>>>(p8, x1f, g3, be3, x2f, x2b);

    // FFN
    gemm_sm_k<64, 128><<<dim3(64, 8), 256, 0, stream>>>(
        x2b, W1b, b1, nullptr, nullptr, nullptr, hb, 4096, 1024, 512, 1);
    gemm_sm_k<64, 64><<<dim3(64, 8), 256, 0, stream>>>(
        hb, W2b, b2, nullptr, nullptr, p8, nullptr, 4096, 512, 1024, 0);
    ln_k<<<4096, 256, 0, stream>>>(p8, x2f, g2, be2, nullptr, x3b);

    // vocab projection: 256x256 4-phase GEMM, 16x125 = 2000 blocks
    gemm256_k<<<dim3(16, 125), 512, 131072, stream>>>(x3b, Woutb, bout, out,
                                                      4096, 32000, 512);
}